// Round 15
// baseline (340.697 us; speedup 1.0000x reference)
//
#include <hip/hip_runtime.h>
#include <hip/hip_bf16.h>
#include <math.h>

#define NB 128
#define NH 1024
#define NL 512
#define OC 64
#define NE 8
#define ND 1024
#define CAPACITY 24

// ---- workspace layout (float offsets) ----
static const size_t WS_PART  = 0;          // conv pooled partials [4][128][1024]; later Y partials [2ks][8e][128b][1024d]
static const size_t WS_WSEP  = 1048576;    // frag-ordered bf16 split weights (dead after conv; clobbered by Y)
static const size_t WS_PXT   = 2097152;    // pooled_xT [1024][128]
static const size_t WS_HPOOL = 2228224;    // h_pool [128][1024]
static const size_t WS_SCALE = 2359296;    // [1024]
static const size_t WS_SHIFT = 2360320;    // [1024]
static const size_t WS_TKW   = 2377728;    // [128][8]
static const size_t WS_TKI   = 2378752;    // int [128][8]
static const size_t WS_USAGE = 2379784;    // [8]
static const size_t WS_VARU  = 2379792;
static const size_t WS_REG   = 2379793;
static const size_t WS_CNT   = 2379794;    // [8]
static const size_t WS_WMAT  = 2380832;    // [128][8]
static const size_t WS_RW    = 2381856;    // [128][8] softmax probs
static const size_t WS_KP    = 2382880;    // int [128] per-sample k
static const size_t WS_CP    = 2400000;    // conv K-split partials [2kh][4lc][128b][8192] (33.5 MB)
static const size_t WS_END   = WS_CP + 2ull * 4 * 128 * 8192;   // floats

typedef __attribute__((ext_vector_type(8))) short bf16x8;
typedef __attribute__((ext_vector_type(4))) float f32x4;

__device__ __forceinline__ float gelu_exact(float v) {
    return 0.5f * v * (1.0f + erff(v * 0.70710678118654752440f));
}

__device__ __forceinline__ unsigned short f2bf_rne(float f) {
    unsigned int u = __float_as_uint(f);
    unsigned int r = u + 0x7FFFu + ((u >> 16) & 1u);
    return (unsigned short)(r >> 16);
}
__device__ __forceinline__ float bf2f(unsigned short h) {
    return __uint_as_float(((unsigned int)h) << 16);
}

__device__ __forceinline__ unsigned cvtpk_bf16(float a, float b) {
    unsigned r;
    asm("v_cvt_pk_bf16_f32 %0, %1, %2" : "=v"(r) : "v"(a), "v"(b));
    return r;
}

// ---- split conv weights into bf16 hi/lo in MFMA-fragment order (coalesced 16B stores) ----
__global__ __launch_bounds__(256) void k_wsplit(const float* __restrict__ cw, float* __restrict__ ws)
{
    if (blockIdx.x == 0 && threadIdx.x == 0) ws[WS_REG] = 0.0f;
    unsigned short* wsep = (unsigned short*)(ws + WS_WSEP);
    int i = blockIdx.x * 256 + threadIdx.x;   // 49152 units of 8 shorts
    int lane = i & 63;
    int split = (i >> 6) & 1;
    int mt = (i >> 7) & 3;
    int rest = i >> 9;                        // 0..95
    int j = rest % 3;
    int it = rest / 3;
    int o = mt * 16 + (lane & 15);
    int hb = it * 32 + ((lane >> 4) << 3);
    unsigned short v8[8];
#pragma unroll
    for (int e = 0; e < 8; ++e) {
        float v = cw[((size_t)o * 1024 + hb + e) * 3 + j];
        unsigned short hi = f2bf_rne(v);
        v8[e] = split ? f2bf_rne(v - bf2f(hi)) : hi;
    }
    *(uint4*)(wsep + ((size_t)((it * 3 + j) * 4 + mt) * 2 + split) * 512 + lane * 8) = *(uint4*)v8;
}

// convert one (4h x 4l) unit of staged f32 -> pair-packed bf16 hi/lo in LDS
__device__ __forceinline__ void cvt_unit(unsigned int* X, int lq, int h4,
                                         const float4* v, float* sh)
{
    sh[0] = sh[1] = sh[2] = sh[3] = 0.f;
#pragma unroll
    for (int i = 0; i < 4; ++i) {
        float a0 = ((const float*)&v[0])[i];
        float a1 = ((const float*)&v[1])[i];
        float a2 = ((const float*)&v[2])[i];
        float a3 = ((const float*)&v[3])[i];
        sh[0] += a0; sh[1] += a1; sh[2] += a2; sh[3] += a3;
        unsigned h01 = cvtpk_bf16(a0, a1);
        unsigned h23 = cvtpk_bf16(a2, a3);
        float r0 = a0 - __uint_as_float(h01 << 16);
        float r1 = a1 - __uint_as_float(h01 & 0xFFFF0000u);
        float r2 = a2 - __uint_as_float(h23 << 16);
        float r3 = a3 - __uint_as_float(h23 & 0xFFFF0000u);
        unsigned l01 = cvtpk_bf16(r0, r1);
        unsigned l23 = cvtpk_bf16(r2, r3);
        int r = lq * 4 + i;
        unsigned int* dst = X + r * 34 + ((2 * h4) ^ ((r & 3) << 2));
        *(uint2*)dst = make_uint2(h01, h23);
        *(uint2*)(dst + 16) = make_uint2(l01, l23);
    }
}

// ---- conv1d via bf16-split MFMA ----
// SPLIT=2: K-split over h (2x 16 its), r12 tile/cvt/swizzle/MFMA-order; arch-VGPR trimmed
// (1-deep x prefetch issued after MFMA, per-j A loads) so total regs incl acc <= 128
// -> 4 waves/SIMD under launch_bounds(256,4). SPLIT=1 fallback keeps bounds (256,2).
template<int SPLIT>
__global__ __launch_bounds__(256, (SPLIT == 2) ? 4 : 2) void k_convmfma(const float* __restrict__ x,
                                                                        const float* __restrict__ cb,
                                                                        float* __restrict__ ws)
{
    __shared__ unsigned int Xb[2][136 * 34];
    __shared__ float xs2[3][128];
    __shared__ float scb[64];

    const int NIT = 32 / SPLIT;
    const int lc = blockIdx.x, b = blockIdx.y;
    const int kh = (SPLIT == 2) ? blockIdx.z : 0;
    const int l0 = lc * 128;
    const int tid = threadIdx.x;
    const int wv = tid >> 6, lane = tid & 63;
    const int h4 = tid & 7;
    const int lqi = 1 + (tid >> 3);
    const bool has_halo = (tid < 16);
    const int lqh = (tid < 8) ? 0 : 33;
    const bool halo_ok = (tid < 8) ? (lc > 0) : (lc < 3);

    const unsigned short* wsg = (const unsigned short*)(ws + WS_WSEP);
    const float* xbase = x + (size_t)b * (NH * NL);
    float* poolp = ws + WS_PART + ((size_t)(lc * 128 + b)) * 1024 + (size_t)kh * NIT * 32;

    if (SPLIT == 1 && tid < 64) scb[tid] = cb[tid];

    f32x4 acc[4][2];
#pragma unroll
    for (int mt = 0; mt < 4; ++mt)
#pragma unroll
        for (int nt = 0; nt < 2; ++nt) acc[mt][nt] = (f32x4){0.f, 0.f, 0.f, 0.f};

    float4 xc[4], hc[4];

    auto xload = [&](int itL) {
        const int hn = (kh * NIT + itL) * 32;
        const float* p = xbase + (size_t)(hn + h4 * 4) * NL + (l0 - 4 + lqi * 4);
#pragma unroll
        for (int jj = 0; jj < 4; ++jj) xc[jj] = *(const float4*)(p + jj * NL);
        if (has_halo) {
            int gl = l0 - 4 + lqh * 4;
#pragma unroll
            for (int jj = 0; jj < 4; ++jj)
                hc[jj] = halo_ok ? *(const float4*)(xbase + (size_t)(hn + h4 * 4 + jj) * NL + gl)
                                 : make_float4(0.f, 0.f, 0.f, 0.f);
        }
    };

    xload(0);

    for (int it = 0; it < NIT; ++it) {
        unsigned int* Xw = Xb[it & 1];
        {
            float sh[4];
            cvt_unit(Xw, lqi, h4, xc, sh);
#pragma unroll
            for (int jj = 0; jj < 4; ++jj) {
                float s = sh[jj];
                s += __shfl_xor(s, 8, 64);
                s += __shfl_xor(s, 16, 64);
                s += __shfl_xor(s, 32, 64);
                if ((lane >> 3) == 0) xs2[it % 3][wv * 32 + h4 * 4 + jj] = s;
            }
            if (has_halo) { float d[4]; cvt_unit(Xw, lqh, h4, hc, d); }
        }
        __syncthreads();
        if (it > 0 && tid < 32) {
            const float* S = xs2[(it - 1) % 3];
            poolp[(it - 1) * 32 + tid] = S[tid] + S[32 + tid] + S[64 + tid] + S[96 + tid];
        }
        const int g4 = (lane >> 4) << 2;
        const unsigned short* abase = wsg + (size_t)(kh * NIT + it) * 12288 + lane * 8;
#pragma unroll
        for (int j = 0; j < 3; ++j) {
            bf16x8 Ah[4], Al[4];
#pragma unroll
            for (int mt = 0; mt < 4; ++mt) {
                Ah[mt] = *(const bf16x8*)(abase + (size_t)((j * 8 + mt * 2) * 512));
                Al[mt] = *(const bf16x8*)(abase + (size_t)((j * 8 + mt * 2 + 1) * 512));
            }
            bf16x8 Bh[2], Bl[2];
#pragma unroll
            for (int nt = 0; nt < 2; ++nt) {
                int rx = 3 + j + wv * 32 + nt * 16 + (lane & 15);
                const unsigned int* bp = Xw + rx * 34 + (g4 ^ ((rx & 3) << 2));
                Bh[nt] = *(const bf16x8*)bp;
                Bl[nt] = *(const bf16x8*)(bp + 16);
            }
#pragma unroll
            for (int mt = 0; mt < 4; ++mt)
#pragma unroll
                for (int nt = 0; nt < 2; ++nt) {
                    acc[mt][nt] = __builtin_amdgcn_mfma_f32_16x16x32_bf16(Ah[mt], Bh[nt], acc[mt][nt], 0, 0, 0);
                    acc[mt][nt] = __builtin_amdgcn_mfma_f32_16x16x32_bf16(Ah[mt], Bl[nt], acc[mt][nt], 0, 0, 0);
                    acc[mt][nt] = __builtin_amdgcn_mfma_f32_16x16x32_bf16(Al[mt], Bh[nt], acc[mt][nt], 0, 0, 0);
                }
        }
        if (it < NIT - 1) xload(it + 1);   // 1-deep prefetch; x regs dead during MFMA phase
    }
    if (tid < 32) {
        const float* S = xs2[(NIT - 1) % 3];
        poolp[(NIT - 1) * 32 + tid] = S[tid] + S[32 + tid] + S[64 + tid] + S[96 + tid];
    }

    if (SPLIT == 2) {
        // store raw fragment partials: [kh][lc][b][tid*8 + mt*2 + nt] float4
        float* cp = ws + WS_CP + (((size_t)(kh * 4 + lc) * 128 + b) * 2048 + tid * 8) * 4;
#pragma unroll
        for (int mt = 0; mt < 4; ++mt)
#pragma unroll
            for (int nt = 0; nt < 2; ++nt)
                *(f32x4*)(cp + (mt * 2 + nt) * 4) = acc[mt][nt];
    } else {
        // ---- epilogue: bias + exact GELU + pool(32) ----
        const int g = lane >> 4, cidx = lane & 15;
#pragma unroll
        for (int mt = 0; mt < 4; ++mt) {
            float s[4];
#pragma unroll
            for (int r = 0; r < 4; ++r) {
                int o = mt * 16 + g * 4 + r;
                float bo = scb[o];
                s[r] = gelu_exact(acc[mt][0][r] + bo) + gelu_exact(acc[mt][1][r] + bo);
            }
#pragma unroll
            for (int m = 1; m < 16; m <<= 1) {
#pragma unroll
                for (int r = 0; r < 4; ++r) s[r] += __shfl_xor(s[r], m, 64);
            }
            if (cidx == 0) {
#pragma unroll
                for (int r = 0; r < 4; ++r) {
                    int o = mt * 16 + g * 4 + r;
                    ws[WS_HPOOL + (size_t)b * 1024 + o * 16 + lc * 4 + wv] = s[r] * (1.0f / 32.0f);
                }
            }
        }
    }
}

// ---- combine K-split conv partials: add halves + bias + exact GELU + pool(32) (r12 epilogue) ----
__global__ __launch_bounds__(256) void k_conv2(const float* __restrict__ cb,
                                               float* __restrict__ ws)
{
    __shared__ float scb[64];
    const int lc = blockIdx.x, b = blockIdx.y;
    const int tid = threadIdx.x;
    const int wv = tid >> 6, lane = tid & 63;
    if (tid < 64) scb[tid] = cb[tid];
    __syncthreads();

    const float* cp0 = ws + WS_CP + (((size_t)(0 * 4 + lc) * 128 + b) * 2048 + tid * 8) * 4;
    const float* cp1 = ws + WS_CP + (((size_t)(1 * 4 + lc) * 128 + b) * 2048 + tid * 8) * 4;
    f32x4 acc[4][2];
#pragma unroll
    for (int mt = 0; mt < 4; ++mt)
#pragma unroll
        for (int nt = 0; nt < 2; ++nt) {
            f32x4 a0 = *(const f32x4*)(cp0 + (mt * 2 + nt) * 4);
            f32x4 a1 = *(const f32x4*)(cp1 + (mt * 2 + nt) * 4);
            acc[mt][nt] = a0 + a1;
        }

    const int g = lane >> 4, cidx = lane & 15;
#pragma unroll
    for (int mt = 0; mt < 4; ++mt) {
        float s[4];
#pragma unroll
        for (int r = 0; r < 4; ++r) {
            int o = mt * 16 + g * 4 + r;
            float bo = scb[o];
            s[r] = gelu_exact(acc[mt][0][r] + bo) + gelu_exact(acc[mt][1][r] + bo);
        }
#pragma unroll
        for (int m = 1; m < 16; m <<= 1) {
#pragma unroll
            for (int r = 0; r < 4; ++r) s[r] += __shfl_xor(s[r], m, 64);
        }
        if (cidx == 0) {
#pragma unroll
            for (int r = 0; r < 4; ++r) {
                int o = mt * 16 + g * 4 + r;
                ws[WS_HPOOL + (size_t)b * 1024 + o * 16 + lc * 4 + wv] = s[r] * (1.0f / 32.0f);
            }
        }
    }
}

// ---- merged: pooled-x reduce (blocks 0..511, 4 lc chunks) + batch-norm stats (blocks 512..515) ----
__global__ __launch_bounds__(256) void k_mid(const float* __restrict__ g,
                                             const float* __restrict__ bet,
                                             float* __restrict__ ws)
{
    int bx = blockIdx.x;
    if (bx < 512) {
        int id = bx * 256 + threadIdx.x;
        int b = id >> 10, h = id & 1023;
        float s = 0.0f;
#pragma unroll
        for (int lcc = 0; lcc < 4; lcc++) s += ws[WS_PART + ((size_t)(lcc * 128 + b)) * 1024 + h];
        ws[WS_PXT + (size_t)h * 128 + b] = s * (1.0f / 512.0f);
    } else {
        int f = (bx - 512) * 256 + threadIdx.x;
        const float* hp = ws + WS_HPOOL;
        float s = 0.0f;
        for (int b = 0; b < 128; b++) s += hp[(size_t)b * 1024 + f];
        float mu = s * (1.0f / 128.0f);
        float v = 0.0f;
        for (int b = 0; b < 128; b++) { float d = hp[(size_t)b * 1024 + f] - mu; v += d * d; }
        float var = v * (1.0f / 128.0f);
        float sc = g[f] / sqrtf(var + 1e-5f);
        ws[WS_SCALE + f] = sc;
        ws[WS_SHIFT + f] = bet[f] - mu * sc;
    }
}

// ---- fused: Y-GEMM (blocks 0..511, e x 32dt x 2ks, no W dependency) + FC1/FC2/top-k (blocks 512..639) ----
__global__ __launch_bounds__(256) void k_fused(const float* __restrict__ w1,
                                               const float* __restrict__ b1,
                                               const float* __restrict__ w2,
                                               const float* __restrict__ b2,
                                               const float* __restrict__ ew,
                                               const float* __restrict__ eb,
                                               float* __restrict__ ws)
{
    __shared__ float smem[5376];
    const int bx = blockIdx.x;
    const int tid = threadIdx.x;

    if (bx < 512) {
        float* a_s = smem;            // [32][128]
        float* b_s = smem + 4096;     // [32][32]
        float* red2 = smem + 5120;    // [256]
        const int e = bx >> 6, dt = (bx >> 1) & 31, ks = bx & 1;
        const int tb = tid >> 3, td = tid & 7;
        float acc[4][4];
#pragma unroll
        for (int i = 0; i < 4; i++)
#pragma unroll
            for (int j = 0; j < 4; j++) acc[i][j] = 0.0f;
        float ssq = 0.0f;

        const float* pxt = ws + WS_PXT;
        for (int kt = 0; kt < 512; kt += 32) {
            __syncthreads();
            for (int idx = tid; idx < 4096; idx += 256) {
                int kk = idx >> 7, bb = idx & 127;
                a_s[kk * 128 + bb] = pxt[(size_t)(ks * 512 + kt + kk) * 128 + bb];
            }
            for (int idx = tid; idx < 1024; idx += 256) {
                int kk = idx >> 5, d = idx & 31;
                float v = ew[(size_t)e * 1048576 + (size_t)(ks * 512 + kt + kk) * 1024 + dt * 32 + d];
                b_s[kk * 32 + d] = v;
                ssq += v * v;
            }
            __syncthreads();
#pragma unroll 4
            for (int kk = 0; kk < 32; kk++) {
                float4 av = *(const float4*)&a_s[kk * 128 + tb * 4];
                float4 bv = *(const float4*)&b_s[kk * 32 + td * 4];
                float aa[4] = {av.x, av.y, av.z, av.w};
                float bb4[4] = {bv.x, bv.y, bv.z, bv.w};
#pragma unroll
                for (int i = 0; i < 4; i++)
#pragma unroll
                    for (int j = 0; j < 4; j++) acc[i][j] = fmaf(aa[i], bb4[j], acc[i][j]);
            }
        }
        float* outp = ws + WS_PART + ((size_t)(ks * 8 + e) * 128) * 1024 + dt * 32;
#pragma unroll
        for (int i = 0; i < 4; i++) {
            int bb = tb * 4 + i;
            *(float4*)(outp + (size_t)bb * 1024 + td * 4) =
                make_float4(acc[i][0], acc[i][1], acc[i][2], acc[i][3]);
        }
        if (bx == 0)
            for (int i = tid; i < 8192; i += 256) { float v = eb[i]; ssq += v * v; }
        red2[tid] = ssq;
        __syncthreads();
        for (int off = 128; off > 0; off >>= 1) {
            if (tid < off) red2[tid] += red2[tid + off];
            __syncthreads();
        }
        if (tid == 0) atomicAdd(ws + WS_REG, red2[0]);
    } else {
        float* hb  = smem;            // [1024]
        float* red = smem + 1024;     // [256]
        float* ha  = smem + 1280;     // [128]
        float* w2s = smem + 1408;     // [1024]
        float* lg  = smem + 2432;     // [8]
        const int b = bx - 512;
        const float* hp = ws + WS_HPOOL + (size_t)b * 1024;
        for (int k = tid; k < 1024; k += 256)
            hb[k] = hp[k] * ws[WS_SCALE + k] + ws[WS_SHIFT + k];
        for (int i = tid; i < 1024; i += 256) w2s[i] = w2[i];
        __syncthreads();
        int o = tid & 127, kh = tid >> 7;
        const float4* wrp = (const float4*)(w1 + (size_t)o * 1024 + kh * 512);
        const float* hx = hb + kh * 512;
        float acc = 0.0f;
#pragma unroll 4
        for (int k = 0; k < 128; k++) {
            float4 w = wrp[k];
            acc = fmaf(hx[4 * k], w.x, acc);     acc = fmaf(hx[4 * k + 1], w.y, acc);
            acc = fmaf(hx[4 * k + 2], w.z, acc); acc = fmaf(hx[4 * k + 3], w.w, acc);
        }
        red[tid] = acc;
        __syncthreads();
        if (tid < 128)
            ha[tid] = gelu_exact(red[tid] + red[tid + 128] + b1[tid]);
        __syncthreads();
        if (tid < 8) {
            float a2 = b2[tid];
            for (int k = 0; k < 128; k++) a2 = fmaf(ha[k], w2s[tid * 128 + k], a2);
            lg[tid] = a2;
        }
        __syncthreads();
        if (tid == 0) {
            float rw[8];
            float m = -1e30f;
#pragma unroll
            for (int e = 0; e < 8; e++) m = fmaxf(m, lg[e]);
            float s = 0.0f;
#pragma unroll
            for (int e = 0; e < 8; e++) { rw[e] = expf(lg[e] - m); s += rw[e]; }
            float inv = 1.0f / s;
#pragma unroll
            for (int e = 0; e < 8; e++) { rw[e] *= inv; ws[WS_RW + b * 8 + e] = rw[e]; }
            float tw[8]; int ti[8]; unsigned used = 0;
#pragma unroll
            for (int r = 0; r < 8; r++) {
                float bv = -1e30f; int bi = 0;
#pragma unroll
                for (int e = 0; e < 8; e++) {
                    bool take = !((used >> e) & 1u) && (rw[e] > bv);
                    bv = take ? rw[e] : bv;
                    bi = take ? e : bi;
                }
                used |= (1u << bi);
                tw[r] = bv; ti[r] = bi;
            }
            float cum = 0.0f; int kp = 8;
#pragma unroll
            for (int r = 0; r < 8; r++) {
                cum += tw[r];
                if (cum > 0.8f) { kp = r + 1; break; }
            }
#pragma unroll
            for (int r = 0; r < 8; r++) {
                ws[WS_TKW + b * 8 + r] = tw[r];
                ((int*)ws)[WS_TKI + b * 8 + r] = ti[r];
            }
            ((int*)ws)[WS_KP + b] = kp;
        }
    }
}

// ---- route: max_k + capacity + usage/var + combine weights (small, 1 block) ----
__global__ __launch_bounds__(128) void k_route(float* __restrict__ ws)
{
    __shared__ float tkw_s[1024];
    __shared__ int   tki_s[1024];
    __shared__ int   keep_s[1024];
    __shared__ float wv_s[128];
    __shared__ int   sv_s[128];
    __shared__ float usg[8];
    __shared__ int   cnt_s[8];
    __shared__ int   mk;

    const int tid = threadIdx.x;
    const int b = tid;
    if (tid == 0) mk = 0;
    if (tid < 8) cnt_s[tid] = 0;
    __syncthreads();
    atomicMax(&mk, ((const int*)ws)[WS_KP + b]);
#pragma unroll
    for (int r = 0; r < 8; r++) {
        tkw_s[b * 8 + r] = ws[WS_TKW + b * 8 + r];
        tki_s[b * 8 + r] = ((const int*)ws)[WS_TKI + b * 8 + r];
    }
    __syncthreads();
    const int maxk = mk;

    if (tid < 8) {
        float s2 = 0.0f;
        for (int bb = 0; bb < 128; bb++) s2 += ws[WS_RW + bb * 8 + tid];
        float u = s2 * (1.0f / 128.0f);
        usg[tid] = u;
        ws[WS_USAGE + tid] = u;
    }
    __syncthreads();
    if (tid == 0) {
        float mu = 0.0f;
#pragma unroll
        for (int e = 0; e < 8; e++) mu += usg[e];
        mu *= (1.0f / 8.0f);
        float v = 0.0f;
#pragma unroll
        for (int e = 0; e < 8; e++) { float d = usg[e] - mu; v += d * d; }
        ws[WS_VARU] = v * (1.0f / 7.0f);
    }

    for (int e = 0; e < 8; ++e) {
        float myw = 0.0f; int mys = -1;
        for (int k = 0; k < maxk; k++)
            if (tki_s[b * 8 + k] == e) { myw = tkw_s[b * 8 + k]; mys = b * 8 + k; }
        wv_s[b] = myw; sv_s[b] = mys;
        __syncthreads();
        if (mys >= 0) {
            int rank = 0;
            for (int b2 = 0; b2 < 128; b2++) {
                int s2 = sv_s[b2];
                if (s2 >= 0) {
                    float w2v = wv_s[b2];
                    if (w2v > myw || (w2v == myw && s2 < mys)) rank++;
                }
            }
            int kept = (rank < CAPACITY) ? 1 : 0;
            keep_s[mys] = kept;
            if (kept) atomicAdd(&cnt_s[e], 1);
        }
        __syncthreads();
    }
    if (tid < 8) ws[WS_CNT + tid] = (float)cnt_s[tid];

    float lv[8]; int kept[8]; int idx[8];
#pragma unroll
    for (int k = 0; k < 8; k++) {
        if (k < maxk) {
            kept[k] = keep_s[b * 8 + k];
            idx[k] = tki_s[b * 8 + k];
            lv[k] = kept[k] ? tkw_s[b * 8 + k] : 0.0f;
        } else { kept[k] = 0; idx[k] = -1; lv[k] = -1e30f; }
    }
    float mx = -1e30f;
#pragma unroll
    for (int k = 0; k < 8; k++) if (k < maxk) mx = fmaxf(mx, lv[k]);
    float s3 = 0.0f; float ev[8];
#pragma unroll
    for (int k = 0; k < 8; k++) { ev[k] = (k < maxk) ? expf(lv[k] - mx) : 0.0f; s3 += ev[k]; }
    float inv3 = 1.0f / s3;
    float Wr[8] = {0, 0, 0, 0, 0, 0, 0, 0};
#pragma unroll
    for (int k = 0; k < 8; k++) {
        if (kept[k]) {
            float v = ev[k] * inv3;
#pragma unroll
            for (int e = 0; e < 8; e++) Wr[e] += (idx[k] == e) ? v : 0.0f;
        }
    }
#pragma unroll
    for (int e = 0; e < 8; e++) ws[WS_WMAT + b * 8 + e] = Wr[e];
}

// ---- final: W-weighted combine of Y partials + expert bias + scalar outputs (float4) ----
__global__ __launch_bounds__(256) void k_final(const float* __restrict__ eb,
                                               const float* __restrict__ ws,
                                               float* __restrict__ out)
{
    int id = blockIdx.x * 256 + threadIdx.x;   // 32768 quads
    int b = id >> 8, dq = id & 255;
    const float* wm = ws + WS_WMAT + b * 8;
    const float* Y = ws + WS_PART;
    float4 s = make_float4(0.f, 0.f, 0.f, 0.f);
#pragma unroll
    for (int e = 0; e < 8; e++) {
        float4 y0 = *(const float4*)(Y + ((size_t)e * 128 + b) * 1024 + dq * 4);
        float4 y1 = *(const float4*)(Y + ((size_t)(8 + e) * 128 + b) * 1024 + dq * 4);
        float4 bb = *(const float4*)(eb + (size_t)e * 1024 + dq * 4);
        float w = wm[e];
        s.x += w * (y0.x + y1.x + bb.x);
        s.y += w * (y0.y + y1.y + bb.y);
        s.z += w * (y0.z + y1.z + bb.z);
        s.w += w * (y0.w + y1.w + bb.w);
    }
    *(float4*)(out + (size_t)b * 1024 + dq * 4) = s;
    if (blockIdx.x == 0) {
        int t = threadIdx.x;
        if (t == 0) out[131072] = 0.005f * ws[WS_VARU] + 1e-6f * ws[WS_REG];
        else if (t >= 1 && t < 9)  out[131072 + t] = ws[WS_USAGE + t - 1];
        else if (t >= 9 && t < 17) out[131072 + t] = ws[WS_CNT + t - 9];
    }
}

extern "C" void kernel_launch(void* const* d_in, const int* in_sizes, int n_in,
                              void* d_out, int out_size, void* d_ws, size_t ws_size,
                              hipStream_t stream)
{
    const float* x   = (const float*)d_in[0];
    const float* cw  = (const float*)d_in[1];
    const float* cb  = (const float*)d_in[2];
    const float* bng = (const float*)d_in[3];
    const float* bnb = (const float*)d_in[4];
    const float* f1w = (const float*)d_in[5];
    const float* f1b = (const float*)d_in[6];
    const float* f2w = (const float*)d_in[7];
    const float* f2b = (const float*)d_in[8];
    const float* ew  = (const float*)d_in[9];
    const float* eb  = (const float*)d_in[10];
    float* ws  = (float*)d_ws;
    float* out = (float*)d_out;

    const bool split_ok = ws_size >= (size_t)WS_END * sizeof(float);

    k_wsplit<<<192, 256, 0, stream>>>(cw, ws);
    if (split_ok) {
        k_convmfma<2><<<dim3(4, 128, 2), 256, 0, stream>>>(x, cb, ws);
        k_conv2<<<dim3(4, 128), 256, 0, stream>>>(cb, ws);
    } else {
        k_convmfma<1><<<dim3(4, 128), 256, 0, stream>>>(x, cb, ws);
    }
    k_mid  <<<516, 256, 0, stream>>>(bng, bnb, ws);
    k_fused<<<640, 256, 0, stream>>>(f1w, f1b, f2w, f2b, ew, eb, ws);
    k_route<<<1, 128, 0, stream>>>(ws);
    k_final<<<128, 256, 0, stream>>>(eb, ws, out);
}

// Round 16
// 312.023 us; speedup vs baseline: 1.0919x; 1.0919x over previous
//
#include <hip/hip_runtime.h>
#include <hip/hip_bf16.h>
#include <math.h>

#define NB 128
#define NH 1024
#define NL 512
#define OC 64
#define NE 8
#define ND 1024
#define CAPACITY 24

// ---- workspace layout (float offsets) ----
static const size_t WS_PART  = 0;          // conv pooled partials [4][128][1024]; later Y partials [2ks][8e][128b][1024d]
static const size_t WS_WSEP  = 1048576;    // frag-ordered bf16 split weights (dead after conv; clobbered by Y)
static const size_t WS_PXT   = 2097152;    // pooled_xT [1024][128]
static const size_t WS_HPOOL = 2228224;    // h_pool [128][1024]
static const size_t WS_SCALE = 2359296;    // [1024]
static const size_t WS_SHIFT = 2360320;    // [1024]
static const size_t WS_TKW   = 2377728;    // [128][8]
static const size_t WS_TKI   = 2378752;    // int [128][8]
static const size_t WS_USAGE = 2379784;    // [8]
static const size_t WS_VARU  = 2379792;
static const size_t WS_REG   = 2379793;
static const size_t WS_CNT   = 2379794;    // [8]
static const size_t WS_WMAT  = 2380832;    // [128][8]
static const size_t WS_RW    = 2381856;    // [128][8] softmax probs
static const size_t WS_KP    = 2382880;    // int [128] per-sample k

typedef __attribute__((ext_vector_type(8))) short bf16x8;
typedef __attribute__((ext_vector_type(4))) float f32x4;

__device__ __forceinline__ float gelu_exact(float v) {
    return 0.5f * v * (1.0f + erff(v * 0.70710678118654752440f));
}

__device__ __forceinline__ unsigned short f2bf_rne(float f) {
    unsigned int u = __float_as_uint(f);
    unsigned int r = u + 0x7FFFu + ((u >> 16) & 1u);
    return (unsigned short)(r >> 16);
}
__device__ __forceinline__ float bf2f(unsigned short h) {
    return __uint_as_float(((unsigned int)h) << 16);
}

__device__ __forceinline__ unsigned cvtpk_bf16(float a, float b) {
    unsigned r;
    asm("v_cvt_pk_bf16_f32 %0, %1, %2" : "=v"(r) : "v"(a), "v"(b));
    return r;
}

// ---- split conv weights into bf16 hi/lo in MFMA-fragment order (coalesced 16B stores) ----
// dst short index: (((it*3 + j)*4 + mt)*2 + split)*512 + lane*8 + e
// source element: o = mt*16 + (lane&15), h = it*32 + (lane>>4)*8 + e, tap j
__global__ __launch_bounds__(256) void k_wsplit(const float* __restrict__ cw, float* __restrict__ ws)
{
    if (blockIdx.x == 0 && threadIdx.x == 0) ws[WS_REG] = 0.0f;
    unsigned short* wsep = (unsigned short*)(ws + WS_WSEP);
    int i = blockIdx.x * 256 + threadIdx.x;   // 49152 units of 8 shorts
    int lane = i & 63;
    int split = (i >> 6) & 1;
    int mt = (i >> 7) & 3;
    int rest = i >> 9;                        // 0..95
    int j = rest % 3;
    int it = rest / 3;
    int o = mt * 16 + (lane & 15);
    int hb = it * 32 + ((lane >> 4) << 3);
    unsigned short v8[8];
#pragma unroll
    for (int e = 0; e < 8; ++e) {
        float v = cw[((size_t)o * 1024 + hb + e) * 3 + j];
        unsigned short hi = f2bf_rne(v);
        v8[e] = split ? f2bf_rne(v - bf2f(hi)) : hi;
    }
    *(uint4*)(wsep + ((size_t)((it * 3 + j) * 4 + mt) * 2 + split) * 512 + lane * 8) = *(uint4*)v8;
}

// convert one (4h x 4l) unit of staged f32 -> pair-packed bf16 hi/lo in LDS
// X row = l-index (stride 34 dwords): dwords [0..15] hi pairs, [16..31] lo pairs, XOR-swizzled
__device__ __forceinline__ void cvt_unit(unsigned int* X, int lq, int h4,
                                         const float4* v, float* sh)
{
    sh[0] = sh[1] = sh[2] = sh[3] = 0.f;
#pragma unroll
    for (int i = 0; i < 4; ++i) {
        float a0 = ((const float*)&v[0])[i];
        float a1 = ((const float*)&v[1])[i];
        float a2 = ((const float*)&v[2])[i];
        float a3 = ((const float*)&v[3])[i];
        sh[0] += a0; sh[1] += a1; sh[2] += a2; sh[3] += a3;
        unsigned h01 = cvtpk_bf16(a0, a1);
        unsigned h23 = cvtpk_bf16(a2, a3);
        float r0 = a0 - __uint_as_float(h01 << 16);
        float r1 = a1 - __uint_as_float(h01 & 0xFFFF0000u);
        float r2 = a2 - __uint_as_float(h23 << 16);
        float r3 = a3 - __uint_as_float(h23 & 0xFFFF0000u);
        unsigned l01 = cvtpk_bf16(r0, r1);
        unsigned l23 = cvtpk_bf16(r2, r3);
        int r = lq * 4 + i;
        unsigned int* dst = X + r * 34 + ((2 * h4) ^ ((r & 3) << 2));
        *(uint2*)dst = make_uint2(h01, h23);
        *(uint2*)(dst + 16) = make_uint2(l01, l23);
    }
}

// ---- conv1d via bf16-split MFMA (round-7/12 proven config: 163 us) ----
// Grid (4 lc, 128 b), 256 thr; x regs 2-deep prefetch, X LDS dbuf, batched A-loads, 1 barrier/it.
__global__ __launch_bounds__(256, 2) void k_convmfma(const float* __restrict__ x,
                                                     const float* __restrict__ cb,
                                                     float* __restrict__ ws)
{
    __shared__ unsigned int Xb[2][136 * 34];
    __shared__ float xs2[3][128];
    __shared__ float scb[64];

    const int lc = blockIdx.x, b = blockIdx.y;
    const int l0 = lc * 128;
    const int tid = threadIdx.x;
    const int wv = tid >> 6, lane = tid & 63;
    const int h4 = tid & 7;
    const int lqi = 1 + (tid >> 3);
    const bool has_halo = (tid < 16);
    const int lqh = (tid < 8) ? 0 : 33;
    const bool halo_ok = (tid < 8) ? (lc > 0) : (lc < 3);

    const unsigned short* wsg = (const unsigned short*)(ws + WS_WSEP);
    const float* xbase = x + (size_t)b * (NH * NL);
    float* poolp = ws + WS_PART + ((size_t)(lc * 128 + b)) * 1024;

    if (tid < 64) scb[tid] = cb[tid];

    f32x4 acc[4][2];
#pragma unroll
    for (int mt = 0; mt < 4; ++mt)
#pragma unroll
        for (int nt = 0; nt < 2; ++nt) acc[mt][nt] = (f32x4){0.f, 0.f, 0.f, 0.f};

    float4 xA[4], hA[4], xB[4], hB[4];

    auto xload = [&](int itL, float4* xc, float4* hc) {
        const int hn = itL * 32;
        const float* p = xbase + (size_t)(hn + h4 * 4) * NL + (l0 - 4 + lqi * 4);
#pragma unroll
        for (int jj = 0; jj < 4; ++jj) xc[jj] = *(const float4*)(p + jj * NL);
        if (has_halo) {
            int gl = l0 - 4 + lqh * 4;
#pragma unroll
            for (int jj = 0; jj < 4; ++jj)
                hc[jj] = halo_ok ? *(const float4*)(xbase + (size_t)(hn + h4 * 4 + jj) * NL + gl)
                                 : make_float4(0.f, 0.f, 0.f, 0.f);
        }
    };

    auto body = [&](int it, float4* xc, float4* hc) {
        unsigned int* Xw = Xb[it & 1];
        bf16x8 Ar[3][4][2];
        {
            const unsigned short* abase = wsg + (size_t)it * 12288 + lane * 8;
#pragma unroll
            for (int j = 0; j < 3; ++j)
#pragma unroll
                for (int mt = 0; mt < 4; ++mt) {
                    Ar[j][mt][0] = *(const bf16x8*)(abase + (size_t)((j * 8 + mt * 2) * 512));
                    Ar[j][mt][1] = *(const bf16x8*)(abase + (size_t)((j * 8 + mt * 2 + 1) * 512));
                }
        }
        {
            float sh[4];
            cvt_unit(Xw, lqi, h4, xc, sh);
#pragma unroll
            for (int jj = 0; jj < 4; ++jj) {
                float s = sh[jj];
                s += __shfl_xor(s, 8, 64);
                s += __shfl_xor(s, 16, 64);
                s += __shfl_xor(s, 32, 64);
                if ((lane >> 3) == 0) xs2[it % 3][wv * 32 + h4 * 4 + jj] = s;
            }
            if (has_halo) { float d[4]; cvt_unit(Xw, lqh, h4, hc, d); }
        }
        __syncthreads();
        if (it > 0 && tid < 32) {
            const float* S = xs2[(it - 1) % 3];
            poolp[(it - 1) * 32 + tid] = S[tid] + S[32 + tid] + S[64 + tid] + S[96 + tid];
        }
        if (it < 30) xload(it + 2, xc, hc);
        const int g4 = (lane >> 4) << 2;
#pragma unroll
        for (int j = 0; j < 3; ++j) {
            bf16x8 Bh[2], Bl[2];
#pragma unroll
            for (int nt = 0; nt < 2; ++nt) {
                int rx = 3 + j + wv * 32 + nt * 16 + (lane & 15);
                const unsigned int* bp = Xw + rx * 34 + (g4 ^ ((rx & 3) << 2));
                Bh[nt] = *(const bf16x8*)bp;
                Bl[nt] = *(const bf16x8*)(bp + 16);
            }
#pragma unroll
            for (int mt = 0; mt < 4; ++mt)
#pragma unroll
                for (int nt = 0; nt < 2; ++nt) {
                    acc[mt][nt] = __builtin_amdgcn_mfma_f32_16x16x32_bf16(Ar[j][mt][0], Bh[nt], acc[mt][nt], 0, 0, 0);
                    acc[mt][nt] = __builtin_amdgcn_mfma_f32_16x16x32_bf16(Ar[j][mt][0], Bl[nt], acc[mt][nt], 0, 0, 0);
                    acc[mt][nt] = __builtin_amdgcn_mfma_f32_16x16x32_bf16(Ar[j][mt][1], Bh[nt], acc[mt][nt], 0, 0, 0);
                }
        }
    };

    xload(0, xA, hA);
    xload(1, xB, hB);

    for (int it2 = 0; it2 < 32; it2 += 2) {
        body(it2, xA, hA);
        body(it2 + 1, xB, hB);
    }
    if (tid < 32) {
        const float* S = xs2[31 % 3];
        poolp[31 * 32 + tid] = S[tid] + S[32 + tid] + S[64 + tid] + S[96 + tid];
    }

    // ---- epilogue: bias + exact GELU + pool(32) ----
    {
        const int g = lane >> 4, cidx = lane & 15;
#pragma unroll
        for (int mt = 0; mt < 4; ++mt) {
            float s[4];
#pragma unroll
            for (int r = 0; r < 4; ++r) {
                int o = mt * 16 + g * 4 + r;
                float bo = scb[o];
                s[r] = gelu_exact(acc[mt][0][r] + bo) + gelu_exact(acc[mt][1][r] + bo);
            }
#pragma unroll
            for (int m = 1; m < 16; m <<= 1) {
#pragma unroll
                for (int r = 0; r < 4; ++r) s[r] += __shfl_xor(s[r], m, 64);
            }
            if (cidx == 0) {
#pragma unroll
                for (int r = 0; r < 4; ++r) {
                    int o = mt * 16 + g * 4 + r;
                    ws[WS_HPOOL + (size_t)b * 1024 + o * 16 + lc * 4 + wv] = s[r] * (1.0f / 32.0f);
                }
            }
        }
    }
}

// ---- merged: pooled-x reduce (blocks 0..511, 4 lc chunks) + batch-norm stats (blocks 512..515) ----
__global__ __launch_bounds__(256) void k_mid(const float* __restrict__ g,
                                             const float* __restrict__ bet,
                                             float* __restrict__ ws)
{
    int bx = blockIdx.x;
    if (bx < 512) {
        int id = bx * 256 + threadIdx.x;
        int b = id >> 10, h = id & 1023;
        float s = 0.0f;
#pragma unroll
        for (int lcc = 0; lcc < 4; lcc++) s += ws[WS_PART + ((size_t)(lcc * 128 + b)) * 1024 + h];
        ws[WS_PXT + (size_t)h * 128 + b] = s * (1.0f / 512.0f);
    } else {
        int f = (bx - 512) * 256 + threadIdx.x;
        const float* hp = ws + WS_HPOOL;
        float s = 0.0f;
        for (int b = 0; b < 128; b++) s += hp[(size_t)b * 1024 + f];
        float mu = s * (1.0f / 128.0f);
        float v = 0.0f;
        for (int b = 0; b < 128; b++) { float d = hp[(size_t)b * 1024 + f] - mu; v += d * d; }
        float var = v * (1.0f / 128.0f);
        float sc = g[f] / sqrtf(var + 1e-5f);
        ws[WS_SCALE + f] = sc;
        ws[WS_SHIFT + f] = bet[f] - mu * sc;
    }
}

// ---- fused: Y-GEMM (blocks 0..511, e x 32dt x 2ks, no W dependency) + FC1/FC2/top-k (blocks 512..639) ----
__global__ __launch_bounds__(256) void k_fused(const float* __restrict__ w1,
                                               const float* __restrict__ b1,
                                               const float* __restrict__ w2,
                                               const float* __restrict__ b2,
                                               const float* __restrict__ ew,
                                               const float* __restrict__ eb,
                                               float* __restrict__ ws)
{
    __shared__ float smem[5376];
    const int bx = blockIdx.x;
    const int tid = threadIdx.x;

    if (bx < 512) {
        float* a_s = smem;            // [32][128]
        float* b_s = smem + 4096;     // [32][32]
        float* red2 = smem + 5120;    // [256]
        const int e = bx >> 6, dt = (bx >> 1) & 31, ks = bx & 1;
        const int tb = tid >> 3, td = tid & 7;
        float acc[4][4];
#pragma unroll
        for (int i = 0; i < 4; i++)
#pragma unroll
            for (int j = 0; j < 4; j++) acc[i][j] = 0.0f;
        float ssq = 0.0f;

        const float* pxt = ws + WS_PXT;
        for (int kt = 0; kt < 512; kt += 32) {
            __syncthreads();
            for (int idx = tid; idx < 4096; idx += 256) {
                int kk = idx >> 7, bb = idx & 127;
                a_s[kk * 128 + bb] = pxt[(size_t)(ks * 512 + kt + kk) * 128 + bb];
            }
            for (int idx = tid; idx < 1024; idx += 256) {
                int kk = idx >> 5, d = idx & 31;
                float v = ew[(size_t)e * 1048576 + (size_t)(ks * 512 + kt + kk) * 1024 + dt * 32 + d];
                b_s[kk * 32 + d] = v;
                ssq += v * v;
            }
            __syncthreads();
#pragma unroll 4
            for (int kk = 0; kk < 32; kk++) {
                float4 av = *(const float4*)&a_s[kk * 128 + tb * 4];
                float4 bv = *(const float4*)&b_s[kk * 32 + td * 4];
                float aa[4] = {av.x, av.y, av.z, av.w};
                float bb4[4] = {bv.x, bv.y, bv.z, bv.w};
#pragma unroll
                for (int i = 0; i < 4; i++)
#pragma unroll
                    for (int j = 0; j < 4; j++) acc[i][j] = fmaf(aa[i], bb4[j], acc[i][j]);
            }
        }
        float* outp = ws + WS_PART + ((size_t)(ks * 8 + e) * 128) * 1024 + dt * 32;
#pragma unroll
        for (int i = 0; i < 4; i++) {
            int bb = tb * 4 + i;
            *(float4*)(outp + (size_t)bb * 1024 + td * 4) =
                make_float4(acc[i][0], acc[i][1], acc[i][2], acc[i][3]);
        }
        if (bx == 0)
            for (int i = tid; i < 8192; i += 256) { float v = eb[i]; ssq += v * v; }
        red2[tid] = ssq;
        __syncthreads();
        for (int off = 128; off > 0; off >>= 1) {
            if (tid < off) red2[tid] += red2[tid + off];
            __syncthreads();
        }
        if (tid == 0) atomicAdd(ws + WS_REG, red2[0]);
    } else {
        float* hb  = smem;            // [1024]
        float* red = smem + 1024;     // [256]
        float* ha  = smem + 1280;     // [128]
        float* w2s = smem + 1408;     // [1024]
        float* lg  = smem + 2432;     // [8]
        const int b = bx - 512;
        const float* hp = ws + WS_HPOOL + (size_t)b * 1024;
        for (int k = tid; k < 1024; k += 256)
            hb[k] = hp[k] * ws[WS_SCALE + k] + ws[WS_SHIFT + k];
        for (int i = tid; i < 1024; i += 256) w2s[i] = w2[i];
        __syncthreads();
        int o = tid & 127, kh = tid >> 7;
        const float4* wrp = (const float4*)(w1 + (size_t)o * 1024 + kh * 512);
        const float* hx = hb + kh * 512;
        float acc = 0.0f;
#pragma unroll 4
        for (int k = 0; k < 128; k++) {
            float4 w = wrp[k];
            acc = fmaf(hx[4 * k], w.x, acc);     acc = fmaf(hx[4 * k + 1], w.y, acc);
            acc = fmaf(hx[4 * k + 2], w.z, acc); acc = fmaf(hx[4 * k + 3], w.w, acc);
        }
        red[tid] = acc;
        __syncthreads();
        if (tid < 128)
            ha[tid] = gelu_exact(red[tid] + red[tid + 128] + b1[tid]);
        __syncthreads();
        if (tid < 8) {
            float a2 = b2[tid];
            for (int k = 0; k < 128; k++) a2 = fmaf(ha[k], w2s[tid * 128 + k], a2);
            lg[tid] = a2;
        }
        __syncthreads();
        if (tid == 0) {
            float rw[8];
            float m = -1e30f;
#pragma unroll
            for (int e = 0; e < 8; e++) m = fmaxf(m, lg[e]);
            float s = 0.0f;
#pragma unroll
            for (int e = 0; e < 8; e++) { rw[e] = expf(lg[e] - m); s += rw[e]; }
            float inv = 1.0f / s;
#pragma unroll
            for (int e = 0; e < 8; e++) { rw[e] *= inv; ws[WS_RW + b * 8 + e] = rw[e]; }
            float tw[8]; int ti[8]; unsigned used = 0;
#pragma unroll
            for (int r = 0; r < 8; r++) {
                float bv = -1e30f; int bi = 0;
#pragma unroll
                for (int e = 0; e < 8; e++) {
                    bool take = !((used >> e) & 1u) && (rw[e] > bv);
                    bv = take ? rw[e] : bv;
                    bi = take ? e : bi;
                }
                used |= (1u << bi);
                tw[r] = bv; ti[r] = bi;
            }
            float cum = 0.0f; int kp = 8;
#pragma unroll
            for (int r = 0; r < 8; r++) {
                cum += tw[r];
                if (cum > 0.8f) { kp = r + 1; break; }
            }
#pragma unroll
            for (int r = 0; r < 8; r++) {
                ws[WS_TKW + b * 8 + r] = tw[r];
                ((int*)ws)[WS_TKI + b * 8 + r] = ti[r];
            }
            ((int*)ws)[WS_KP + b] = kp;
        }
    }
}

// ---- route: max_k + capacity + usage/var + combine weights (small, 1 block) ----
__global__ __launch_bounds__(128) void k_route(float* __restrict__ ws)
{
    __shared__ float tkw_s[1024];
    __shared__ int   tki_s[1024];
    __shared__ int   keep_s[1024];
    __shared__ float wv_s[128];
    __shared__ int   sv_s[128];
    __shared__ float usg[8];
    __shared__ int   cnt_s[8];
    __shared__ int   mk;

    const int tid = threadIdx.x;
    const int b = tid;
    if (tid == 0) mk = 0;
    if (tid < 8) cnt_s[tid] = 0;
    __syncthreads();
    atomicMax(&mk, ((const int*)ws)[WS_KP + b]);
#pragma unroll
    for (int r = 0; r < 8; r++) {
        tkw_s[b * 8 + r] = ws[WS_TKW + b * 8 + r];
        tki_s[b * 8 + r] = ((const int*)ws)[WS_TKI + b * 8 + r];
    }
    __syncthreads();
    const int maxk = mk;

    if (tid < 8) {
        float s2 = 0.0f;
        for (int bb = 0; bb < 128; bb++) s2 += ws[WS_RW + bb * 8 + tid];
        float u = s2 * (1.0f / 128.0f);
        usg[tid] = u;
        ws[WS_USAGE + tid] = u;
    }
    __syncthreads();
    if (tid == 0) {
        float mu = 0.0f;
#pragma unroll
        for (int e = 0; e < 8; e++) mu += usg[e];
        mu *= (1.0f / 8.0f);
        float v = 0.0f;
#pragma unroll
        for (int e = 0; e < 8; e++) { float d = usg[e] - mu; v += d * d; }
        ws[WS_VARU] = v * (1.0f / 7.0f);
    }

    for (int e = 0; e < 8; ++e) {
        float myw = 0.0f; int mys = -1;
        for (int k = 0; k < maxk; k++)
            if (tki_s[b * 8 + k] == e) { myw = tkw_s[b * 8 + k]; mys = b * 8 + k; }
        wv_s[b] = myw; sv_s[b] = mys;
        __syncthreads();
        if (mys >= 0) {
            int rank = 0;
            for (int b2 = 0; b2 < 128; b2++) {
                int s2 = sv_s[b2];
                if (s2 >= 0) {
                    float w2v = wv_s[b2];
                    if (w2v > myw || (w2v == myw && s2 < mys)) rank++;
                }
            }
            int kept = (rank < CAPACITY) ? 1 : 0;
            keep_s[mys] = kept;
            if (kept) atomicAdd(&cnt_s[e], 1);
        }
        __syncthreads();
    }
    if (tid < 8) ws[WS_CNT + tid] = (float)cnt_s[tid];

    float lv[8]; int kept[8]; int idx[8];
#pragma unroll
    for (int k = 0; k < 8; k++) {
        if (k < maxk) {
            kept[k] = keep_s[b * 8 + k];
            idx[k] = tki_s[b * 8 + k];
            lv[k] = kept[k] ? tkw_s[b * 8 + k] : 0.0f;
        } else { kept[k] = 0; idx[k] = -1; lv[k] = -1e30f; }
    }
    float mx = -1e30f;
#pragma unroll
    for (int k = 0; k < 8; k++) if (k < maxk) mx = fmaxf(mx, lv[k]);
    float s3 = 0.0f; float ev[8];
#pragma unroll
    for (int k = 0; k < 8; k++) { ev[k] = (k < maxk) ? expf(lv[k] - mx) : 0.0f; s3 += ev[k]; }
    float inv3 = 1.0f / s3;
    float Wr[8] = {0, 0, 0, 0, 0, 0, 0, 0};
#pragma unroll
    for (int k = 0; k < 8; k++) {
        if (kept[k]) {
            float v = ev[k] * inv3;
#pragma unroll
            for (int e = 0; e < 8; e++) Wr[e] += (idx[k] == e) ? v : 0.0f;
        }
    }
#pragma unroll
    for (int e = 0; e < 8; e++) ws[WS_WMAT + b * 8 + e] = Wr[e];
}

// ---- final: W-weighted combine of Y partials + expert bias + scalar outputs (float4) ----
__global__ __launch_bounds__(256) void k_final(const float* __restrict__ eb,
                                               const float* __restrict__ ws,
                                               float* __restrict__ out)
{
    int id = blockIdx.x * 256 + threadIdx.x;   // 32768 quads
    int b = id >> 8, dq = id & 255;
    const float* wm = ws + WS_WMAT + b * 8;
    const float* Y = ws + WS_PART;
    float4 s = make_float4(0.f, 0.f, 0.f, 0.f);
#pragma unroll
    for (int e = 0; e < 8; e++) {
        float4 y0 = *(const float4*)(Y + ((size_t)e * 128 + b) * 1024 + dq * 4);
        float4 y1 = *(const float4*)(Y + ((size_t)(8 + e) * 128 + b) * 1024 + dq * 4);
        float4 bb = *(const float4*)(eb + (size_t)e * 1024 + dq * 4);
        float w = wm[e];
        s.x += w * (y0.x + y1.x + bb.x);
        s.y += w * (y0.y + y1.y + bb.y);
        s.z += w * (y0.z + y1.z + bb.z);
        s.w += w * (y0.w + y1.w + bb.w);
    }
    *(float4*)(out + (size_t)b * 1024 + dq * 4) = s;
    if (blockIdx.x == 0) {
        int t = threadIdx.x;
        if (t == 0) out[131072] = 0.005f * ws[WS_VARU] + 1e-6f * ws[WS_REG];
        else if (t >= 1 && t < 9)  out[131072 + t] = ws[WS_USAGE + t - 1];
        else if (t >= 9 && t < 17) out[131072 + t] = ws[WS_CNT + t - 9];
    }
}

extern "C" void kernel_launch(void* const* d_in, const int* in_sizes, int n_in,
                              void* d_out, int out_size, void* d_ws, size_t ws_size,
                              hipStream_t stream)
{
    const float* x   = (const float*)d_in[0];
    const float* cw  = (const float*)d_in[1];
    const float* cb  = (const float*)d_in[2];
    const float* bng = (const float*)d_in[3];
    const float* bnb = (const float*)d_in[4];
    const float* f1w = (const float*)d_in[5];
    const float* f1b = (const float*)d_in[6];
    const float* f2w = (const float*)d_in[7];
    const float* f2b = (const float*)d_in[8];
    const float* ew  = (const float*)d_in[9];
    const float* eb  = (const float*)d_in[10];
    float* ws  = (float*)d_ws;
    float* out = (float*)d_out;

    k_wsplit<<<192, 256, 0, stream>>>(cw, ws);
    k_convmfma<<<dim3(4, 128), 256, 0, stream>>>(x, cb, ws);
    k_mid  <<<516, 256, 0, stream>>>(bng, bnb, ws);
    k_fused<<<640, 256, 0, stream>>>(f1w, f1b, f2w, f2b, ew, eb, ws);
    k_route<<<1, 128, 0, stream>>>(ws);
    k_final<<<128, 256, 0, stream>>>(eb, ws, out);
}

// Round 17
// 299.397 us; speedup vs baseline: 1.1379x; 1.0422x over previous
//
#include <hip/hip_runtime.h>
#include <hip/hip_bf16.h>
#include <math.h>

#define NB 128
#define NH 1024
#define NL 512
#define OC 64
#define NE 8
#define ND 1024
#define CAPACITY 24

// ---- workspace layout (float offsets) ----
static const size_t WS_PART  = 0;          // conv pooled partials [4][128][1024]
static const size_t WS_WSEP  = 1048576;    // frag-ordered bf16 split weights
static const size_t WS_HPOOL = 2228224;    // h_pool [128][1024]
static const size_t WS_TKW   = 2377728;    // [128][8]
static const size_t WS_TKI   = 2378752;    // int [128][8]
static const size_t WS_REG   = 2379793;
static const size_t WS_RW    = 2381856;    // [128][8] softmax probs
static const size_t WS_KP    = 2382880;    // int [128] per-sample k
static const size_t WS_Y     = 2400000;    // Y partials [2ks][8e][128b][1024d] (region proven available in r14)

typedef __attribute__((ext_vector_type(8))) short bf16x8;
typedef __attribute__((ext_vector_type(4))) float f32x4;

__device__ __forceinline__ float gelu_exact(float v) {
    return 0.5f * v * (1.0f + erff(v * 0.70710678118654752440f));
}

__device__ __forceinline__ unsigned short f2bf_rne(float f) {
    unsigned int u = __float_as_uint(f);
    unsigned int r = u + 0x7FFFu + ((u >> 16) & 1u);
    return (unsigned short)(r >> 16);
}
__device__ __forceinline__ float bf2f(unsigned short h) {
    return __uint_as_float(((unsigned int)h) << 16);
}

__device__ __forceinline__ unsigned cvtpk_bf16(float a, float b) {
    unsigned r;
    asm("v_cvt_pk_bf16_f32 %0, %1, %2" : "=v"(r) : "v"(a), "v"(b));
    return r;
}

// ---- split conv weights into bf16 hi/lo in MFMA-fragment order (coalesced 16B stores) ----
__global__ __launch_bounds__(256) void k_wsplit(const float* __restrict__ cw, float* __restrict__ ws)
{
    if (blockIdx.x == 0 && threadIdx.x == 0) ws[WS_REG] = 0.0f;
    unsigned short* wsep = (unsigned short*)(ws + WS_WSEP);
    int i = blockIdx.x * 256 + threadIdx.x;   // 49152 units of 8 shorts
    int lane = i & 63;
    int split = (i >> 6) & 1;
    int mt = (i >> 7) & 3;
    int rest = i >> 9;                        // 0..95
    int j = rest % 3;
    int it = rest / 3;
    int o = mt * 16 + (lane & 15);
    int hb = it * 32 + ((lane >> 4) << 3);
    unsigned short v8[8];
#pragma unroll
    for (int e = 0; e < 8; ++e) {
        float v = cw[((size_t)o * 1024 + hb + e) * 3 + j];
        unsigned short hi = f2bf_rne(v);
        v8[e] = split ? f2bf_rne(v - bf2f(hi)) : hi;
    }
    *(uint4*)(wsep + ((size_t)((it * 3 + j) * 4 + mt) * 2 + split) * 512 + lane * 8) = *(uint4*)v8;
}

// convert one (4h x 4l) unit of staged f32 -> pair-packed bf16 hi/lo in LDS
__device__ __forceinline__ void cvt_unit(unsigned int* X, int lq, int h4,
                                         const float4* v, float* sh)
{
    sh[0] = sh[1] = sh[2] = sh[3] = 0.f;
#pragma unroll
    for (int i = 0; i < 4; ++i) {
        float a0 = ((const float*)&v[0])[i];
        float a1 = ((const float*)&v[1])[i];
        float a2 = ((const float*)&v[2])[i];
        float a3 = ((const float*)&v[3])[i];
        sh[0] += a0; sh[1] += a1; sh[2] += a2; sh[3] += a3;
        unsigned h01 = cvtpk_bf16(a0, a1);
        unsigned h23 = cvtpk_bf16(a2, a3);
        float r0 = a0 - __uint_as_float(h01 << 16);
        float r1 = a1 - __uint_as_float(h01 & 0xFFFF0000u);
        float r2 = a2 - __uint_as_float(h23 << 16);
        float r3 = a3 - __uint_as_float(h23 & 0xFFFF0000u);
        unsigned l01 = cvtpk_bf16(r0, r1);
        unsigned l23 = cvtpk_bf16(r2, r3);
        int r = lq * 4 + i;
        unsigned int* dst = X + r * 34 + ((2 * h4) ^ ((r & 3) << 2));
        *(uint2*)dst = make_uint2(h01, h23);
        *(uint2*)(dst + 16) = make_uint2(l01, l23);
    }
}

// ---- conv1d via bf16-split MFMA (round-7/12 proven config, byte-identical) ----
__global__ __launch_bounds__(256, 2) void k_convmfma(const float* __restrict__ x,
                                                     const float* __restrict__ cb,
                                                     float* __restrict__ ws)
{
    __shared__ unsigned int Xb[2][136 * 34];
    __shared__ float xs2[3][128];
    __shared__ float scb[64];

    const int lc = blockIdx.x, b = blockIdx.y;
    const int l0 = lc * 128;
    const int tid = threadIdx.x;
    const int wv = tid >> 6, lane = tid & 63;
    const int h4 = tid & 7;
    const int lqi = 1 + (tid >> 3);
    const bool has_halo = (tid < 16);
    const int lqh = (tid < 8) ? 0 : 33;
    const bool halo_ok = (tid < 8) ? (lc > 0) : (lc < 3);

    const unsigned short* wsg = (const unsigned short*)(ws + WS_WSEP);
    const float* xbase = x + (size_t)b * (NH * NL);
    float* poolp = ws + WS_PART + ((size_t)(lc * 128 + b)) * 1024;

    if (tid < 64) scb[tid] = cb[tid];

    f32x4 acc[4][2];
#pragma unroll
    for (int mt = 0; mt < 4; ++mt)
#pragma unroll
        for (int nt = 0; nt < 2; ++nt) acc[mt][nt] = (f32x4){0.f, 0.f, 0.f, 0.f};

    float4 xA[4], hA[4], xB[4], hB[4];

    auto xload = [&](int itL, float4* xc, float4* hc) {
        const int hn = itL * 32;
        const float* p = xbase + (size_t)(hn + h4 * 4) * NL + (l0 - 4 + lqi * 4);
#pragma unroll
        for (int jj = 0; jj < 4; ++jj) xc[jj] = *(const float4*)(p + jj * NL);
        if (has_halo) {
            int gl = l0 - 4 + lqh * 4;
#pragma unroll
            for (int jj = 0; jj < 4; ++jj)
                hc[jj] = halo_ok ? *(const float4*)(xbase + (size_t)(hn + h4 * 4 + jj) * NL + gl)
                                 : make_float4(0.f, 0.f, 0.f, 0.f);
        }
    };

    auto body = [&](int it, float4* xc, float4* hc) {
        unsigned int* Xw = Xb[it & 1];
        bf16x8 Ar[3][4][2];
        {
            const unsigned short* abase = wsg + (size_t)it * 12288 + lane * 8;
#pragma unroll
            for (int j = 0; j < 3; ++j)
#pragma unroll
                for (int mt = 0; mt < 4; ++mt) {
                    Ar[j][mt][0] = *(const bf16x8*)(abase + (size_t)((j * 8 + mt * 2) * 512));
                    Ar[j][mt][1] = *(const bf16x8*)(abase + (size_t)((j * 8 + mt * 2 + 1) * 512));
                }
        }
        {
            float sh[4];
            cvt_unit(Xw, lqi, h4, xc, sh);
#pragma unroll
            for (int jj = 0; jj < 4; ++jj) {
                float s = sh[jj];
                s += __shfl_xor(s, 8, 64);
                s += __shfl_xor(s, 16, 64);
                s += __shfl_xor(s, 32, 64);
                if ((lane >> 3) == 0) xs2[it % 3][wv * 32 + h4 * 4 + jj] = s;
            }
            if (has_halo) { float d[4]; cvt_unit(Xw, lqh, h4, hc, d); }
        }
        __syncthreads();
        if (it > 0 && tid < 32) {
            const float* S = xs2[(it - 1) % 3];
            poolp[(it - 1) * 32 + tid] = S[tid] + S[32 + tid] + S[64 + tid] + S[96 + tid];
        }
        if (it < 30) xload(it + 2, xc, hc);
        const int g4 = (lane >> 4) << 2;
#pragma unroll
        for (int j = 0; j < 3; ++j) {
            bf16x8 Bh[2], Bl[2];
#pragma unroll
            for (int nt = 0; nt < 2; ++nt) {
                int rx = 3 + j + wv * 32 + nt * 16 + (lane & 15);
                const unsigned int* bp = Xw + rx * 34 + (g4 ^ ((rx & 3) << 2));
                Bh[nt] = *(const bf16x8*)bp;
                Bl[nt] = *(const bf16x8*)(bp + 16);
            }
#pragma unroll
            for (int mt = 0; mt < 4; ++mt)
#pragma unroll
                for (int nt = 0; nt < 2; ++nt) {
                    acc[mt][nt] = __builtin_amdgcn_mfma_f32_16x16x32_bf16(Ar[j][mt][0], Bh[nt], acc[mt][nt], 0, 0, 0);
                    acc[mt][nt] = __builtin_amdgcn_mfma_f32_16x16x32_bf16(Ar[j][mt][0], Bl[nt], acc[mt][nt], 0, 0, 0);
                    acc[mt][nt] = __builtin_amdgcn_mfma_f32_16x16x32_bf16(Ar[j][mt][1], Bh[nt], acc[mt][nt], 0, 0, 0);
                }
        }
    };

    xload(0, xA, hA);
    xload(1, xB, hB);

    for (int it2 = 0; it2 < 32; it2 += 2) {
        body(it2, xA, hA);
        body(it2 + 1, xB, hB);
    }
    if (tid < 32) {
        const float* S = xs2[31 % 3];
        poolp[31 * 32 + tid] = S[tid] + S[32 + tid] + S[64 + tid] + S[96 + tid];
    }

    // ---- epilogue: bias + exact GELU + pool(32) ----
    {
        const int g = lane >> 4, cidx = lane & 15;
#pragma unroll
        for (int mt = 0; mt < 4; ++mt) {
            float s[4];
#pragma unroll
            for (int r = 0; r < 4; ++r) {
                int o = mt * 16 + g * 4 + r;
                float bo = scb[o];
                s[r] = gelu_exact(acc[mt][0][r] + bo) + gelu_exact(acc[mt][1][r] + bo);
            }
#pragma unroll
            for (int m = 1; m < 16; m <<= 1) {
#pragma unroll
                for (int r = 0; r < 4; ++r) s[r] += __shfl_xor(s[r], m, 64);
            }
            if (cidx == 0) {
#pragma unroll
                for (int r = 0; r < 4; ++r) {
                    int o = mt * 16 + g * 4 + r;
                    ws[WS_HPOOL + (size_t)b * 1024 + o * 16 + lc * 4 + wv] = s[r] * (1.0f / 32.0f);
                }
            }
        }
    }
}

// ---- fused: Y-GEMM (blocks 0..511, stages A from 4 conv partials) + BN+FC1/FC2/top-k (blocks 512..639) ----
__global__ __launch_bounds__(256) void k_fused(const float* __restrict__ w1,
                                               const float* __restrict__ b1,
                                               const float* __restrict__ w2,
                                               const float* __restrict__ b2,
                                               const float* __restrict__ ew,
                                               const float* __restrict__ eb,
                                               const float* __restrict__ bng,
                                               const float* __restrict__ bnb,
                                               float* __restrict__ ws)
{
    __shared__ float smem[5504];
    const int bx = blockIdx.x;
    const int tid = threadIdx.x;

    if (bx < 512) {
        float* a_s = smem;            // [32][132] padded
        float* b_s = smem + 4224;     // [32][32]
        float* red2 = smem + 5248;    // [256]
        const int e = bx >> 6, dt = (bx >> 1) & 31, ks = bx & 1;
        const int tb = tid >> 3, td = tid & 7;
        float acc[4][4];
#pragma unroll
        for (int i = 0; i < 4; i++)
#pragma unroll
            for (int j = 0; j < 4; j++) acc[i][j] = 0.0f;
        float ssq = 0.0f;

        const float* P = ws + WS_PART;
        for (int kt = 0; kt < 512; kt += 32) {
            __syncthreads();
            for (int idx = tid; idx < 4096; idx += 256) {
                int bb = idx >> 5, hh = idx & 31;
                size_t hoff = (size_t)(ks * 512 + kt + hh);
                float s = P[((size_t)(0 * 128 + bb)) * 1024 + hoff];
                s += P[((size_t)(1 * 128 + bb)) * 1024 + hoff];
                s += P[((size_t)(2 * 128 + bb)) * 1024 + hoff];
                s += P[((size_t)(3 * 128 + bb)) * 1024 + hoff];
                a_s[hh * 132 + bb] = s * (1.0f / 512.0f);
            }
            for (int idx = tid; idx < 1024; idx += 256) {
                int kk = idx >> 5, d = idx & 31;
                float v = ew[(size_t)e * 1048576 + (size_t)(ks * 512 + kt + kk) * 1024 + dt * 32 + d];
                b_s[kk * 32 + d] = v;
                ssq += v * v;
            }
            __syncthreads();
#pragma unroll 4
            for (int kk = 0; kk < 32; kk++) {
                float4 av = *(const float4*)&a_s[kk * 132 + tb * 4];
                float4 bv = *(const float4*)&b_s[kk * 32 + td * 4];
                float aa[4] = {av.x, av.y, av.z, av.w};
                float bb4[4] = {bv.x, bv.y, bv.z, bv.w};
#pragma unroll
                for (int i = 0; i < 4; i++)
#pragma unroll
                    for (int j = 0; j < 4; j++) acc[i][j] = fmaf(aa[i], bb4[j], acc[i][j]);
            }
        }
        float* outp = ws + WS_Y + ((size_t)(ks * 8 + e) * 128) * 1024 + dt * 32;
#pragma unroll
        for (int i = 0; i < 4; i++) {
            int bb = tb * 4 + i;
            *(float4*)(outp + (size_t)bb * 1024 + td * 4) =
                make_float4(acc[i][0], acc[i][1], acc[i][2], acc[i][3]);
        }
        if (bx == 0)
            for (int i = tid; i < 8192; i += 256) { float v = eb[i]; ssq += v * v; }
        red2[tid] = ssq;
        __syncthreads();
        for (int off = 128; off > 0; off >>= 1) {
            if (tid < off) red2[tid] += red2[tid + off];
            __syncthreads();
        }
        if (tid == 0) atomicAdd(ws + WS_REG, red2[0]);
    } else {
        float* hb   = smem;            // [1024]
        float* red  = smem + 1024;     // [256]
        float* ha   = smem + 1280;     // [128]
        float* w2s  = smem + 1408;     // [1024]
        float* lg   = smem + 2432;     // [8]
        float* sc_s = smem + 2440;     // [1024]
        float* sh_s = smem + 3464;     // [1024]
        const int b = bx - 512;

        // in-block BN stats (bitwise-identical to old k_mid: b-ascending two-pass)
        {
            const float* hpa = ws + WS_HPOOL;
            int f0 = tid * 4;
            float s0 = 0.f, s1 = 0.f, s2 = 0.f, s3 = 0.f;
            for (int b2 = 0; b2 < 128; ++b2) {
                float4 v = *(const float4*)(hpa + (size_t)b2 * 1024 + f0);
                s0 += v.x; s1 += v.y; s2 += v.z; s3 += v.w;
            }
            float mu0 = s0 * (1.0f / 128.0f), mu1 = s1 * (1.0f / 128.0f);
            float mu2 = s2 * (1.0f / 128.0f), mu3 = s3 * (1.0f / 128.0f);
            float v0 = 0.f, v1 = 0.f, v2 = 0.f, v3 = 0.f;
            for (int b2 = 0; b2 < 128; ++b2) {
                float4 v = *(const float4*)(hpa + (size_t)b2 * 1024 + f0);
                float d0 = v.x - mu0, d1 = v.y - mu1, d2 = v.z - mu2, d3 = v.w - mu3;
                v0 += d0 * d0; v1 += d1 * d1; v2 += d2 * d2; v3 += d3 * d3;
            }
            float4 g4 = *(const float4*)(bng + f0);
            float4 be4 = *(const float4*)(bnb + f0);
            float sc0 = g4.x / sqrtf(v0 * (1.0f / 128.0f) + 1e-5f);
            float sc1 = g4.y / sqrtf(v1 * (1.0f / 128.0f) + 1e-5f);
            float sc2 = g4.z / sqrtf(v2 * (1.0f / 128.0f) + 1e-5f);
            float sc3 = g4.w / sqrtf(v3 * (1.0f / 128.0f) + 1e-5f);
            sc_s[f0] = sc0; sc_s[f0 + 1] = sc1; sc_s[f0 + 2] = sc2; sc_s[f0 + 3] = sc3;
            sh_s[f0] = be4.x - mu0 * sc0;
            sh_s[f0 + 1] = be4.y - mu1 * sc1;
            sh_s[f0 + 2] = be4.z - mu2 * sc2;
            sh_s[f0 + 3] = be4.w - mu3 * sc3;
        }
        for (int i = tid; i < 1024; i += 256) w2s[i] = w2[i];
        __syncthreads();

        const float* hp = ws + WS_HPOOL + (size_t)b * 1024;
        for (int k = tid; k < 1024; k += 256)
            hb[k] = hp[k] * sc_s[k] + sh_s[k];
        __syncthreads();
        int o = tid & 127, kh = tid >> 7;
        const float4* wrp = (const float4*)(w1 + (size_t)o * 1024 + kh * 512);
        const float* hx = hb + kh * 512;
        float acc = 0.0f;
#pragma unroll 4
        for (int k = 0; k < 128; k++) {
            float4 w = wrp[k];
            acc = fmaf(hx[4 * k], w.x, acc);     acc = fmaf(hx[4 * k + 1], w.y, acc);
            acc = fmaf(hx[4 * k + 2], w.z, acc); acc = fmaf(hx[4 * k + 3], w.w, acc);
        }
        red[tid] = acc;
        __syncthreads();
        if (tid < 128)
            ha[tid] = gelu_exact(red[tid] + red[tid + 128] + b1[tid]);
        __syncthreads();
        if (tid < 8) {
            float a2 = b2[tid];
            for (int k = 0; k < 128; k++) a2 = fmaf(ha[k], w2s[tid * 128 + k], a2);
            lg[tid] = a2;
        }
        __syncthreads();
        if (tid == 0) {
            float rw[8];
            float m = -1e30f;
#pragma unroll
            for (int e = 0; e < 8; e++) m = fmaxf(m, lg[e]);
            float s = 0.0f;
#pragma unroll
            for (int e = 0; e < 8; e++) { rw[e] = expf(lg[e] - m); s += rw[e]; }
            float inv = 1.0f / s;
#pragma unroll
            for (int e = 0; e < 8; e++) { rw[e] *= inv; ws[WS_RW + b * 8 + e] = rw[e]; }
            float tw[8]; int ti[8]; unsigned used = 0;
#pragma unroll
            for (int r = 0; r < 8; r++) {
                float bv = -1e30f; int bi = 0;
#pragma unroll
                for (int e = 0; e < 8; e++) {
                    bool take = !((used >> e) & 1u) && (rw[e] > bv);
                    bv = take ? rw[e] : bv;
                    bi = take ? e : bi;
                }
                used |= (1u << bi);
                tw[r] = bv; ti[r] = bi;
            }
            float cum = 0.0f; int kp = 8;
#pragma unroll
            for (int r = 0; r < 8; r++) {
                cum += tw[r];
                if (cum > 0.8f) { kp = r + 1; break; }
            }
#pragma unroll
            for (int r = 0; r < 8; r++) {
                ws[WS_TKW + b * 8 + r] = tw[r];
                ((int*)ws)[WS_TKI + b * 8 + r] = ti[r];
            }
            ((int*)ws)[WS_KP + b] = kp;
        }
    }
}

// ---- final: in-block routing (capacity + combine) + W-weighted Y combine + scalar outputs ----
__global__ __launch_bounds__(256) void k_final(const float* __restrict__ eb,
                                               const float* __restrict__ ws,
                                               float* __restrict__ out)
{
    __shared__ float tkw_s[1024];
    __shared__ int   tki_s[1024];
    __shared__ int   keep_s[1024];
    __shared__ float wv_s[128];
    __shared__ int   sv_s[128];
    __shared__ float usg[8];
    __shared__ int   cnt_s[8];
    __shared__ int   mk;
    __shared__ float wmat_s[8];
    __shared__ float vu_s;

    const int bx = blockIdx.x;   // sample
    const int tid = threadIdx.x;
    if (tid == 0) mk = 0;
    if (tid < 8) cnt_s[tid] = 0;
    for (int i = tid; i < 1024; i += 256) {
        tkw_s[i] = ws[WS_TKW + i];
        tki_s[i] = ((const int*)ws)[WS_TKI + i];
    }
    __syncthreads();
    if (tid < 128) atomicMax(&mk, ((const int*)ws)[WS_KP + tid]);
    __syncthreads();
    const int maxk = mk;

    for (int e = 0; e < 8; ++e) {
        float myw = 0.0f; int mys = -1;
        if (tid < 128) {
            for (int k = 0; k < maxk; k++)
                if (tki_s[tid * 8 + k] == e) { myw = tkw_s[tid * 8 + k]; mys = tid * 8 + k; }
            wv_s[tid] = myw; sv_s[tid] = mys;
        }
        __syncthreads();
        if (tid < 128 && mys >= 0) {
            int rank = 0;
            for (int b2 = 0; b2 < 128; b2++) {
                int s2 = sv_s[b2];
                if (s2 >= 0) {
                    float w2v = wv_s[b2];
                    if (w2v > myw || (w2v == myw && s2 < mys)) rank++;
                }
            }
            int kept = (rank < CAPACITY) ? 1 : 0;
            keep_s[mys] = kept;
            if (kept) atomicAdd(&cnt_s[e], 1);
        }
        __syncthreads();
    }

    if (tid < 8) {
        float s2 = 0.0f;
        for (int bb = 0; bb < 128; bb++) s2 += ws[WS_RW + bb * 8 + tid];
        usg[tid] = s2 * (1.0f / 128.0f);
    }
    __syncthreads();
    if (tid == 0) {
        // combine weights for this block's sample bx (identical arithmetic to old k_route)
        float lv[8]; int kept[8]; int idx[8];
#pragma unroll
        for (int k = 0; k < 8; k++) {
            if (k < maxk) {
                kept[k] = keep_s[bx * 8 + k];
                idx[k] = tki_s[bx * 8 + k];
                lv[k] = kept[k] ? tkw_s[bx * 8 + k] : 0.0f;
            } else { kept[k] = 0; idx[k] = -1; lv[k] = -1e30f; }
        }
        float mx = -1e30f;
#pragma unroll
        for (int k = 0; k < 8; k++) if (k < maxk) mx = fmaxf(mx, lv[k]);
        float s3 = 0.0f; float ev[8];
#pragma unroll
        for (int k = 0; k < 8; k++) { ev[k] = (k < maxk) ? expf(lv[k] - mx) : 0.0f; s3 += ev[k]; }
        float inv3 = 1.0f / s3;
        float Wr[8] = {0, 0, 0, 0, 0, 0, 0, 0};
#pragma unroll
        for (int k = 0; k < 8; k++) {
            if (kept[k]) {
                float v = ev[k] * inv3;
#pragma unroll
                for (int e = 0; e < 8; e++) Wr[e] += (idx[k] == e) ? v : 0.0f;
            }
        }
#pragma unroll
        for (int e = 0; e < 8; e++) wmat_s[e] = Wr[e];
        // usage variance (ddof=1)
        float mu = 0.0f;
#pragma unroll
        for (int e = 0; e < 8; e++) mu += usg[e];
        mu *= (1.0f / 8.0f);
        float v = 0.0f;
#pragma unroll
        for (int e = 0; e < 8; e++) { float d = usg[e] - mu; v += d * d; }
        vu_s = v * (1.0f / 7.0f);
    }
    __syncthreads();

    // main output: 256 quads of sample bx
    {
        const int dq = tid;
        const float* Y = ws + WS_Y;
        float4 s = make_float4(0.f, 0.f, 0.f, 0.f);
#pragma unroll
        for (int e = 0; e < 8; e++) {
            float4 y0 = *(const float4*)(Y + ((size_t)e * 128 + bx) * 1024 + dq * 4);
            float4 y1 = *(const float4*)(Y + ((size_t)(8 + e) * 128 + bx) * 1024 + dq * 4);
            float4 bb = *(const float4*)(eb + (size_t)e * 1024 + dq * 4);
            float w = wmat_s[e];
            s.x += w * (y0.x + y1.x + bb.x);
            s.y += w * (y0.y + y1.y + bb.y);
            s.z += w * (y0.z + y1.z + bb.z);
            s.w += w * (y0.w + y1.w + bb.w);
        }
        *(float4*)(out + (size_t)bx * 1024 + dq * 4) = s;
    }
    if (bx == 0) {
        int t = tid;
        if (t == 0) out[131072] = 0.005f * vu_s + 1e-6f * ws[WS_REG];
        else if (t >= 1 && t < 9)  out[131072 + t] = usg[t - 1];
        else if (t >= 9 && t < 17) out[131072 + t] = (float)cnt_s[t - 9];
    }
}

extern "C" void kernel_launch(void* const* d_in, const int* in_sizes, int n_in,
                              void* d_out, int out_size, void* d_ws, size_t ws_size,
                              hipStream_t stream)
{
    const float* x   = (const float*)d_in[0];
    const float* cw  = (const float*)d_in[1];
    const float* cb  = (const float*)d_in[2];
    const float* bng = (const float*)d_in[3];
    const float* bnb = (const float*)d_in[4];
    const float* f1w = (const float*)d_in[5];
    const float* f1b = (const float*)d_in[6];
    const float* f2w = (const float*)d_in[7];
    const float* f2b = (const float*)d_in[8];
    const float* ew  = (const float*)d_in[9];
    const float* eb  = (const float*)d_in[10];
    float* ws  = (float*)d_ws;
    float* out = (float*)d_out;

    k_wsplit  <<<192, 256, 0, stream>>>(cw, ws);
    k_convmfma<<<dim3(4, 128), 256, 0, stream>>>(x, cb, ws);
    k_fused   <<<640, 256, 0, stream>>>(f1w, f1b, f2w, f2b, ew, eb, bng, bnb, ws);
    k_final   <<<128, 256, 0, stream>>>(eb, ws, out);
}

// Round 18
// 282.263 us; speedup vs baseline: 1.2070x; 1.0607x over previous
//
#include <hip/hip_runtime.h>
#include <hip/hip_bf16.h>
#include <math.h>

#define NB 128
#define NH 1024
#define NL 512
#define OC 64
#define NE 8
#define ND 1024
#define CAPACITY 24

// ---- workspace layout (float offsets) ----
static const size_t WS_PART  = 0;          // conv pooled partials [4][128][1024]
static const size_t WS_WSEP  = 1048576;    // frag-ordered bf16 split weights
static const size_t WS_POOL  = 2097152;    // pooled [128][1024] (scaled by 1/512)
static const size_t WS_HPOOL = 2228224;    // h_pool [128][1024]
static const size_t WS_TKW   = 2377728;    // [128][8]
static const size_t WS_TKI   = 2378752;    // int [128][8]
static const size_t WS_REG   = 2379793;
static const size_t WS_RW    = 2381856;    // [128][8] softmax probs
static const size_t WS_KP    = 2382880;    // int [128] per-sample k
static const size_t WS_Y     = 2400000;    // Y partials [2ks][8e][128b][1024d]

typedef __attribute__((ext_vector_type(8))) short bf16x8;
typedef __attribute__((ext_vector_type(4))) float f32x4;

__device__ __forceinline__ float gelu_exact(float v) {
    return 0.5f * v * (1.0f + erff(v * 0.70710678118654752440f));
}

__device__ __forceinline__ unsigned short f2bf_rne(float f) {
    unsigned int u = __float_as_uint(f);
    unsigned int r = u + 0x7FFFu + ((u >> 16) & 1u);
    return (unsigned short)(r >> 16);
}
__device__ __forceinline__ float bf2f(unsigned short h) {
    return __uint_as_float(((unsigned int)h) << 16);
}

__device__ __forceinline__ unsigned cvtpk_bf16(float a, float b) {
    unsigned r;
    asm("v_cvt_pk_bf16_f32 %0, %1, %2" : "=v"(r) : "v"(a), "v"(b));
    return r;
}

// ---- split conv weights into bf16 hi/lo in MFMA-fragment order (coalesced 16B stores) ----
__global__ __launch_bounds__(256) void k_wsplit(const float* __restrict__ cw, float* __restrict__ ws)
{
    if (blockIdx.x == 0 && threadIdx.x == 0) ws[WS_REG] = 0.0f;
    unsigned short* wsep = (unsigned short*)(ws + WS_WSEP);
    int i = blockIdx.x * 256 + threadIdx.x;   // 49152 units of 8 shorts
    int lane = i & 63;
    int split = (i >> 6) & 1;
    int mt = (i >> 7) & 3;
    int rest = i >> 9;                        // 0..95
    int j = rest % 3;
    int it = rest / 3;
    int o = mt * 16 + (lane & 15);
    int hb = it * 32 + ((lane >> 4) << 3);
    unsigned short v8[8];
#pragma unroll
    for (int e = 0; e < 8; ++e) {
        float v = cw[((size_t)o * 1024 + hb + e) * 3 + j];
        unsigned short hi = f2bf_rne(v);
        v8[e] = split ? f2bf_rne(v - bf2f(hi)) : hi;
    }
    *(uint4*)(wsep + ((size_t)((it * 3 + j) * 4 + mt) * 2 + split) * 512 + lane * 8) = *(uint4*)v8;
}

// convert one (4h x 4l) unit of staged f32 -> pair-packed bf16 hi/lo in LDS
__device__ __forceinline__ void cvt_unit(unsigned int* X, int lq, int h4,
                                         const float4* v, float* sh)
{
    sh[0] = sh[1] = sh[2] = sh[3] = 0.f;
#pragma unroll
    for (int i = 0; i < 4; ++i) {
        float a0 = ((const float*)&v[0])[i];
        float a1 = ((const float*)&v[1])[i];
        float a2 = ((const float*)&v[2])[i];
        float a3 = ((const float*)&v[3])[i];
        sh[0] += a0; sh[1] += a1; sh[2] += a2; sh[3] += a3;
        unsigned h01 = cvtpk_bf16(a0, a1);
        unsigned h23 = cvtpk_bf16(a2, a3);
        float r0 = a0 - __uint_as_float(h01 << 16);
        float r1 = a1 - __uint_as_float(h01 & 0xFFFF0000u);
        float r2 = a2 - __uint_as_float(h23 << 16);
        float r3 = a3 - __uint_as_float(h23 & 0xFFFF0000u);
        unsigned l01 = cvtpk_bf16(r0, r1);
        unsigned l23 = cvtpk_bf16(r2, r3);
        int r = lq * 4 + i;
        unsigned int* dst = X + r * 34 + ((2 * h4) ^ ((r & 3) << 2));
        *(uint2*)dst = make_uint2(h01, h23);
        *(uint2*)(dst + 16) = make_uint2(l01, l23);
    }
}

// ---- conv1d via bf16-split MFMA (round-7/12 proven config, byte-identical) ----
__global__ __launch_bounds__(256, 2) void k_convmfma(const float* __restrict__ x,
                                                     const float* __restrict__ cb,
                                                     float* __restrict__ ws)
{
    __shared__ unsigned int Xb[2][136 * 34];
    __shared__ float xs2[3][128];
    __shared__ float scb[64];

    const int lc = blockIdx.x, b = blockIdx.y;
    const int l0 = lc * 128;
    const int tid = threadIdx.x;
    const int wv = tid >> 6, lane = tid & 63;
    const int h4 = tid & 7;
    const int lqi = 1 + (tid >> 3);
    const bool has_halo = (tid < 16);
    const int lqh = (tid < 8) ? 0 : 33;
    const bool halo_ok = (tid < 8) ? (lc > 0) : (lc < 3);

    const unsigned short* wsg = (const unsigned short*)(ws + WS_WSEP);
    const float* xbase = x + (size_t)b * (NH * NL);
    float* poolp = ws + WS_PART + ((size_t)(lc * 128 + b)) * 1024;

    if (tid < 64) scb[tid] = cb[tid];

    f32x4 acc[4][2];
#pragma unroll
    for (int mt = 0; mt < 4; ++mt)
#pragma unroll
        for (int nt = 0; nt < 2; ++nt) acc[mt][nt] = (f32x4){0.f, 0.f, 0.f, 0.f};

    float4 xA[4], hA[4], xB[4], hB[4];

    auto xload = [&](int itL, float4* xc, float4* hc) {
        const int hn = itL * 32;
        const float* p = xbase + (size_t)(hn + h4 * 4) * NL + (l0 - 4 + lqi * 4);
#pragma unroll
        for (int jj = 0; jj < 4; ++jj) xc[jj] = *(const float4*)(p + jj * NL);
        if (has_halo) {
            int gl = l0 - 4 + lqh * 4;
#pragma unroll
            for (int jj = 0; jj < 4; ++jj)
                hc[jj] = halo_ok ? *(const float4*)(xbase + (size_t)(hn + h4 * 4 + jj) * NL + gl)
                                 : make_float4(0.f, 0.f, 0.f, 0.f);
        }
    };

    auto body = [&](int it, float4* xc, float4* hc) {
        unsigned int* Xw = Xb[it & 1];
        bf16x8 Ar[3][4][2];
        {
            const unsigned short* abase = wsg + (size_t)it * 12288 + lane * 8;
#pragma unroll
            for (int j = 0; j < 3; ++j)
#pragma unroll
                for (int mt = 0; mt < 4; ++mt) {
                    Ar[j][mt][0] = *(const bf16x8*)(abase + (size_t)((j * 8 + mt * 2) * 512));
                    Ar[j][mt][1] = *(const bf16x8*)(abase + (size_t)((j * 8 + mt * 2 + 1) * 512));
                }
        }
        {
            float sh[4];
            cvt_unit(Xw, lqi, h4, xc, sh);
#pragma unroll
            for (int jj = 0; jj < 4; ++jj) {
                float s = sh[jj];
                s += __shfl_xor(s, 8, 64);
                s += __shfl_xor(s, 16, 64);
                s += __shfl_xor(s, 32, 64);
                if ((lane >> 3) == 0) xs2[it % 3][wv * 32 + h4 * 4 + jj] = s;
            }
            if (has_halo) { float d[4]; cvt_unit(Xw, lqh, h4, hc, d); }
        }
        __syncthreads();
        if (it > 0 && tid < 32) {
            const float* S = xs2[(it - 1) % 3];
            poolp[(it - 1) * 32 + tid] = S[tid] + S[32 + tid] + S[64 + tid] + S[96 + tid];
        }
        if (it < 30) xload(it + 2, xc, hc);
        const int g4 = (lane >> 4) << 2;
#pragma unroll
        for (int j = 0; j < 3; ++j) {
            bf16x8 Bh[2], Bl[2];
#pragma unroll
            for (int nt = 0; nt < 2; ++nt) {
                int rx = 3 + j + wv * 32 + nt * 16 + (lane & 15);
                const unsigned int* bp = Xw + rx * 34 + (g4 ^ ((rx & 3) << 2));
                Bh[nt] = *(const bf16x8*)bp;
                Bl[nt] = *(const bf16x8*)(bp + 16);
            }
#pragma unroll
            for (int mt = 0; mt < 4; ++mt)
#pragma unroll
                for (int nt = 0; nt < 2; ++nt) {
                    acc[mt][nt] = __builtin_amdgcn_mfma_f32_16x16x32_bf16(Ar[j][mt][0], Bh[nt], acc[mt][nt], 0, 0, 0);
                    acc[mt][nt] = __builtin_amdgcn_mfma_f32_16x16x32_bf16(Ar[j][mt][0], Bl[nt], acc[mt][nt], 0, 0, 0);
                    acc[mt][nt] = __builtin_amdgcn_mfma_f32_16x16x32_bf16(Ar[j][mt][1], Bh[nt], acc[mt][nt], 0, 0, 0);
                }
        }
    };

    xload(0, xA, hA);
    xload(1, xB, hB);

    for (int it2 = 0; it2 < 32; it2 += 2) {
        body(it2, xA, hA);
        body(it2 + 1, xB, hB);
    }
    if (tid < 32) {
        const float* S = xs2[31 % 3];
        poolp[31 * 32 + tid] = S[tid] + S[32 + tid] + S[64 + tid] + S[96 + tid];
    }

    // ---- epilogue: bias + exact GELU + pool(32) ----
    {
        const int g = lane >> 4, cidx = lane & 15;
#pragma unroll
        for (int mt = 0; mt < 4; ++mt) {
            float s[4];
#pragma unroll
            for (int r = 0; r < 4; ++r) {
                int o = mt * 16 + g * 4 + r;
                float bo = scb[o];
                s[r] = gelu_exact(acc[mt][0][r] + bo) + gelu_exact(acc[mt][1][r] + bo);
            }
#pragma unroll
            for (int m = 1; m < 16; m <<= 1) {
#pragma unroll
                for (int r = 0; r < 4; ++r) s[r] += __shfl_xor(s[r], m, 64);
            }
            if (cidx == 0) {
#pragma unroll
                for (int r = 0; r < 4; ++r) {
                    int o = mt * 16 + g * 4 + r;
                    ws[WS_HPOOL + (size_t)b * 1024 + o * 16 + lc * 4 + wv] = s[r] * (1.0f / 32.0f);
                }
            }
        }
    }
}

// ---- pooled reduce: sum 4 conv partials once (same order as before -> bitwise identical) ----
__global__ __launch_bounds__(256) void k_pool(float* __restrict__ ws)
{
    int id = blockIdx.x * 256 + threadIdx.x;   // 131072
    int b = id >> 10, h = id & 1023;
    const float* P = ws + WS_PART;
    float s = P[((size_t)(0 * 128 + b)) * 1024 + h];
    s += P[((size_t)(1 * 128 + b)) * 1024 + h];
    s += P[((size_t)(2 * 128 + b)) * 1024 + h];
    s += P[((size_t)(3 * 128 + b)) * 1024 + h];
    ws[WS_POOL + (size_t)b * 1024 + h] = s * (1.0f / 512.0f);
}

// ---- fused: Y-GEMM (blocks 0..511, A from pooled) + BN+FC1/FC2/top-k (blocks 512..639) ----
__global__ __launch_bounds__(256) void k_fused(const float* __restrict__ w1,
                                               const float* __restrict__ b1,
                                               const float* __restrict__ w2,
                                               const float* __restrict__ b2,
                                               const float* __restrict__ ew,
                                               const float* __restrict__ eb,
                                               const float* __restrict__ bng,
                                               const float* __restrict__ bnb,
                                               float* __restrict__ ws)
{
    __shared__ float smem[5504];
    const int bx = blockIdx.x;
    const int tid = threadIdx.x;

    if (bx < 512) {
        float* a_s = smem;            // [32][132] padded
        float* b_s = smem + 4224;     // [32][32]
        float* red2 = smem + 5248;    // [256]
        const int e = bx >> 6, dt = (bx >> 1) & 31, ks = bx & 1;
        const int tb = tid >> 3, td = tid & 7;
        float acc[4][4];
#pragma unroll
        for (int i = 0; i < 4; i++)
#pragma unroll
            for (int j = 0; j < 4; j++) acc[i][j] = 0.0f;
        float ssq = 0.0f;

        const float* pooled = ws + WS_POOL;
        for (int kt = 0; kt < 512; kt += 32) {
            __syncthreads();
            for (int idx = tid; idx < 4096; idx += 256) {
                int bb = idx >> 5, hh = idx & 31;
                a_s[hh * 132 + bb] = pooled[(size_t)bb * 1024 + (ks * 512 + kt + hh)];
            }
            for (int idx = tid; idx < 1024; idx += 256) {
                int kk = idx >> 5, d = idx & 31;
                float v = ew[(size_t)e * 1048576 + (size_t)(ks * 512 + kt + kk) * 1024 + dt * 32 + d];
                b_s[kk * 32 + d] = v;
                ssq += v * v;
            }
            __syncthreads();
#pragma unroll 4
            for (int kk = 0; kk < 32; kk++) {
                float4 av = *(const float4*)&a_s[kk * 132 + tb * 4];
                float4 bv = *(const float4*)&b_s[kk * 32 + td * 4];
                float aa[4] = {av.x, av.y, av.z, av.w};
                float bb4[4] = {bv.x, bv.y, bv.z, bv.w};
#pragma unroll
                for (int i = 0; i < 4; i++)
#pragma unroll
                    for (int j = 0; j < 4; j++) acc[i][j] = fmaf(aa[i], bb4[j], acc[i][j]);
            }
        }
        float* outp = ws + WS_Y + ((size_t)(ks * 8 + e) * 128) * 1024 + dt * 32;
#pragma unroll
        for (int i = 0; i < 4; i++) {
            int bb = tb * 4 + i;
            *(float4*)(outp + (size_t)bb * 1024 + td * 4) =
                make_float4(acc[i][0], acc[i][1], acc[i][2], acc[i][3]);
        }
        if (bx == 0)
            for (int i = tid; i < 8192; i += 256) { float v = eb[i]; ssq += v * v; }
        red2[tid] = ssq;
        __syncthreads();
        for (int off = 128; off > 0; off >>= 1) {
            if (tid < off) red2[tid] += red2[tid + off];
            __syncthreads();
        }
        if (tid == 0) atomicAdd(ws + WS_REG, red2[0]);
    } else {
        float* hb   = smem;            // [1024]
        float* red  = smem + 1024;     // [256]
        float* ha   = smem + 1280;     // [128]
        float* w2s  = smem + 1408;     // [1024]
        float* lg   = smem + 2432;     // [8]
        float* sc_s = smem + 2440;     // [1024]
        float* sh_s = smem + 3464;     // [1024]
        const int b = bx - 512;

        // in-block BN stats (b-ascending two-pass, bitwise-identical)
        {
            const float* hpa = ws + WS_HPOOL;
            int f0 = tid * 4;
            float s0 = 0.f, s1 = 0.f, s2 = 0.f, s3 = 0.f;
            for (int b2 = 0; b2 < 128; ++b2) {
                float4 v = *(const float4*)(hpa + (size_t)b2 * 1024 + f0);
                s0 += v.x; s1 += v.y; s2 += v.z; s3 += v.w;
            }
            float mu0 = s0 * (1.0f / 128.0f), mu1 = s1 * (1.0f / 128.0f);
            float mu2 = s2 * (1.0f / 128.0f), mu3 = s3 * (1.0f / 128.0f);
            float v0 = 0.f, v1 = 0.f, v2 = 0.f, v3 = 0.f;
            for (int b2 = 0; b2 < 128; ++b2) {
                float4 v = *(const float4*)(hpa + (size_t)b2 * 1024 + f0);
                float d0 = v.x - mu0, d1 = v.y - mu1, d2 = v.z - mu2, d3 = v.w - mu3;
                v0 += d0 * d0; v1 += d1 * d1; v2 += d2 * d2; v3 += d3 * d3;
            }
            float4 g4 = *(const float4*)(bng + f0);
            float4 be4 = *(const float4*)(bnb + f0);
            float sc0 = g4.x / sqrtf(v0 * (1.0f / 128.0f) + 1e-5f);
            float sc1 = g4.y / sqrtf(v1 * (1.0f / 128.0f) + 1e-5f);
            float sc2 = g4.z / sqrtf(v2 * (1.0f / 128.0f) + 1e-5f);
            float sc3 = g4.w / sqrtf(v3 * (1.0f / 128.0f) + 1e-5f);
            sc_s[f0] = sc0; sc_s[f0 + 1] = sc1; sc_s[f0 + 2] = sc2; sc_s[f0 + 3] = sc3;
            sh_s[f0] = be4.x - mu0 * sc0;
            sh_s[f0 + 1] = be4.y - mu1 * sc1;
            sh_s[f0 + 2] = be4.z - mu2 * sc2;
            sh_s[f0 + 3] = be4.w - mu3 * sc3;
        }
        for (int i = tid; i < 1024; i += 256) w2s[i] = w2[i];
        __syncthreads();

        const float* hp = ws + WS_HPOOL + (size_t)b * 1024;
        for (int k = tid; k < 1024; k += 256)
            hb[k] = hp[k] * sc_s[k] + sh_s[k];
        __syncthreads();
        int o = tid & 127, kh = tid >> 7;
        const float4* wrp = (const float4*)(w1 + (size_t)o * 1024 + kh * 512);
        const float* hx = hb + kh * 512;
        float acc = 0.0f;
#pragma unroll 4
        for (int k = 0; k < 128; k++) {
            float4 w = wrp[k];
            acc = fmaf(hx[4 * k], w.x, acc);     acc = fmaf(hx[4 * k + 1], w.y, acc);
            acc = fmaf(hx[4 * k + 2], w.z, acc); acc = fmaf(hx[4 * k + 3], w.w, acc);
        }
        red[tid] = acc;
        __syncthreads();
        if (tid < 128)
            ha[tid] = gelu_exact(red[tid] + red[tid + 128] + b1[tid]);
        __syncthreads();
        if (tid < 8) {
            float a2 = b2[tid];
            for (int k = 0; k < 128; k++) a2 = fmaf(ha[k], w2s[tid * 128 + k], a2);
            lg[tid] = a2;
        }
        __syncthreads();
        if (tid == 0) {
            float rw[8];
            float m = -1e30f;
#pragma unroll
            for (int e = 0; e < 8; e++) m = fmaxf(m, lg[e]);
            float s = 0.0f;
#pragma unroll
            for (int e = 0; e < 8; e++) { rw[e] = expf(lg[e] - m); s += rw[e]; }
            float inv = 1.0f / s;
#pragma unroll
            for (int e = 0; e < 8; e++) { rw[e] *= inv; ws[WS_RW + b * 8 + e] = rw[e]; }
            float tw[8]; int ti[8]; unsigned used = 0;
#pragma unroll
            for (int r = 0; r < 8; r++) {
                float bv = -1e30f; int bi = 0;
#pragma unroll
                for (int e = 0; e < 8; e++) {
                    bool take = !((used >> e) & 1u) && (rw[e] > bv);
                    bv = take ? rw[e] : bv;
                    bi = take ? e : bi;
                }
                used |= (1u << bi);
                tw[r] = bv; ti[r] = bi;
            }
            float cum = 0.0f; int kp = 8;
#pragma unroll
            for (int r = 0; r < 8; r++) {
                cum += tw[r];
                if (cum > 0.8f) { kp = r + 1; break; }
            }
#pragma unroll
            for (int r = 0; r < 8; r++) {
                ws[WS_TKW + b * 8 + r] = tw[r];
                ((int*)ws)[WS_TKI + b * 8 + r] = ti[r];
            }
            ((int*)ws)[WS_KP + b] = kp;
        }
    }
}

// ---- final: in-block routing (capacity + combine) + W-weighted Y combine + scalar outputs ----
__global__ __launch_bounds__(256) void k_final(const float* __restrict__ eb,
                                               const float* __restrict__ ws,
                                               float* __restrict__ out)
{
    __shared__ float tkw_s[1024];
    __shared__ int   tki_s[1024];
    __shared__ int   keep_s[1024];
    __shared__ float wv_s[128];
    __shared__ int   sv_s[128];
    __shared__ float usg[8];
    __shared__ int   cnt_s[8];
    __shared__ int   mk;
    __shared__ float wmat_s[8];
    __shared__ float vu_s;

    const int bx = blockIdx.x;   // sample
    const int tid = threadIdx.x;
    if (tid == 0) mk = 0;
    if (tid < 8) cnt_s[tid] = 0;
    for (int i = tid; i < 1024; i += 256) {
        tkw_s[i] = ws[WS_TKW + i];
        tki_s[i] = ((const int*)ws)[WS_TKI + i];
    }
    __syncthreads();
    if (tid < 128) atomicMax(&mk, ((const int*)ws)[WS_KP + tid]);
    __syncthreads();
    const int maxk = mk;

    for (int e = 0; e < 8; ++e) {
        float myw = 0.0f; int mys = -1;
        if (tid < 128) {
            for (int k = 0; k < maxk; k++)
                if (tki_s[tid * 8 + k] == e) { myw = tkw_s[tid * 8 + k]; mys = tid * 8 + k; }
            wv_s[tid] = myw; sv_s[tid] = mys;
        }
        __syncthreads();
        if (tid < 128 && mys >= 0) {
            int rank = 0;
            for (int b2 = 0; b2 < 128; b2++) {
                int s2 = sv_s[b2];
                if (s2 >= 0) {
                    float w2v = wv_s[b2];
                    if (w2v > myw || (w2v == myw && s2 < mys)) rank++;
                }
            }
            int kept = (rank < CAPACITY) ? 1 : 0;
            keep_s[mys] = kept;
            if (kept) atomicAdd(&cnt_s[e], 1);
        }
        __syncthreads();
    }

    if (tid < 8) {
        float s2 = 0.0f;
        for (int bb = 0; bb < 128; bb++) s2 += ws[WS_RW + bb * 8 + tid];
        usg[tid] = s2 * (1.0f / 128.0f);
    }
    __syncthreads();
    if (tid == 0) {
        float lv[8]; int kept[8]; int idx[8];
#pragma unroll
        for (int k = 0; k < 8; k++) {
            if (k < maxk) {
                kept[k] = keep_s[bx * 8 + k];
                idx[k] = tki_s[bx * 8 + k];
                lv[k] = kept[k] ? tkw_s[bx * 8 + k] : 0.0f;
            } else { kept[k] = 0; idx[k] = -1; lv[k] = -1e30f; }
        }
        float mx = -1e30f;
#pragma unroll
        for (int k = 0; k < 8; k++) if (k < maxk) mx = fmaxf(mx, lv[k]);
        float s3 = 0.0f; float ev[8];
#pragma unroll
        for (int k = 0; k < 8; k++) { ev[k] = (k < maxk) ? expf(lv[k] - mx) : 0.0f; s3 += ev[k]; }
        float inv3 = 1.0f / s3;
        float Wr[8] = {0, 0, 0, 0, 0, 0, 0, 0};
#pragma unroll
        for (int k = 0; k < 8; k++) {
            if (kept[k]) {
                float v = ev[k] * inv3;
#pragma unroll
                for (int e = 0; e < 8; e++) Wr[e] += (idx[k] == e) ? v : 0.0f;
            }
        }
#pragma unroll
        for (int e = 0; e < 8; e++) wmat_s[e] = Wr[e];
        float mu = 0.0f;
#pragma unroll
        for (int e = 0; e < 8; e++) mu += usg[e];
        mu *= (1.0f / 8.0f);
        float v = 0.0f;
#pragma unroll
        for (int e = 0; e < 8; e++) { float d = usg[e] - mu; v += d * d; }
        vu_s = v * (1.0f / 7.0f);
    }
    __syncthreads();

    {
        const int dq = tid;
        const float* Y = ws + WS_Y;
        float4 s = make_float4(0.f, 0.f, 0.f, 0.f);
#pragma unroll
        for (int e = 0; e < 8; e++) {
            float4 y0 = *(const float4*)(Y + ((size_t)e * 128 + bx) * 1024 + dq * 4);
            float4 y1 = *(const float4*)(Y + ((size_t)(8 + e) * 128 + bx) * 1024 + dq * 4);
            float4 bb = *(const float4*)(eb + (size_t)e * 1024 + dq * 4);
            float w = wmat_s[e];
            s.x += w * (y0.x + y1.x + bb.x);
            s.y += w * (y0.y + y1.y + bb.y);
            s.z += w * (y0.z + y1.z + bb.z);
            s.w += w * (y0.w + y1.w + bb.w);
        }
        *(float4*)(out + (size_t)bx * 1024 + dq * 4) = s;
    }
    if (bx == 0) {
        int t = tid;
        if (t == 0) out[131072] = 0.005f * vu_s + 1e-6f * ws[WS_REG];
        else if (t >= 1 && t < 9)  out[131072 + t] = usg[t - 1];
        else if (t >= 9 && t < 17) out[131072 + t] = (float)cnt_s[t - 9];
    }
}

extern "C" void kernel_launch(void* const* d_in, const int* in_sizes, int n_in,
                              void* d_out, int out_size, void* d_ws, size_t ws_size,
                              hipStream_t stream)
{
    const float* x   = (const float*)d_in[0];
    const float* cw  = (const float*)d_in[1];
    const float* cb  = (const float*)d_in[2];
    const float* bng = (const float*)d_in[3];
    const float* bnb = (const float*)d_in[4];
    const float* f1w = (const float*)d_in[5];
    const float* f1b = (const float*)d_in[6];
    const float* f2w = (const float*)d_in[7];
    const float* f2b = (const float*)d_in[8];
    const float* ew  = (const float*)d_in[9];
    const float* eb  = (const float*)d_in[10];
    float* ws  = (float*)d_ws;
    float* out = (float*)d_out;

    k_wsplit  <<<192, 256, 0, stream>>>(cw, ws);
    k_convmfma<<<dim3(4, 128), 256, 0, stream>>>(x, cb, ws);
    k_pool    <<<512, 256, 0, stream>>>(ws);
    k_fused   <<<640, 256, 0, stream>>>(f1w, f1b, f2w, f2b, ew, eb, bng, bnb, ws);
    k_final   <<<128, 256, 0, stream>>>(eb, ws, out);
}